// Round 9
// baseline (167.441 us; speedup 1.0000x reference)
//
#include <hip/hip_runtime.h>

// ---------------- problem constants ----------------
#define BATCH 2
#define SEQ 2048
#define DMODEL 2048
#define NHEADS 16
#define NKV 4
#define DK 128
#define WINH 64   // WINDOW/2
#define NQKV 3072 // 2048 q + 512 k + 512 v

typedef unsigned short ushort_t;
typedef __attribute__((ext_vector_type(8))) __bf16 bf16x8;
typedef __attribute__((ext_vector_type(4))) float f32x4;

__device__ __forceinline__ float b2f(ushort_t u) {
    union { unsigned int i; float f; } v; v.i = ((unsigned int)u) << 16; return v.f;
}
__device__ __forceinline__ ushort_t f2b(float f) {
    union { float f; unsigned int i; } v; v.f = f;
    unsigned int r = v.i + 0x7FFFu + ((v.i >> 16) & 1u);
    return (ushort_t)(r >> 16);
}

// async global->LDS, 16B/lane; LDS dest wave-uniform base + lane*16.
__device__ __forceinline__ void gload_lds16(const ushort_t* g, ushort_t* l) {
    __builtin_amdgcn_global_load_lds(
        (__attribute__((address_space(1))) void*)(void*)const_cast<ushort_t*>(g),
        (__attribute__((address_space(3))) void*)l, 16, 0, 0);
}

// ---------------------------------------------------------------
// f32 -> bf16 cast, 8 elements/thread.
// ---------------------------------------------------------------
__global__ __launch_bounds__(256) void cvt_bf16(
    const float* __restrict__ src, ushort_t* __restrict__ dst, int n8)
{
    int i = blockIdx.x * 256 + threadIdx.x;
    if (i >= n8) return;
    float4 a = *((const float4*)src + i * 2);
    float4 b = *((const float4*)src + i * 2 + 1);
    ushort_t o[8] = { f2b(a.x), f2b(a.y), f2b(a.z), f2b(a.w),
                      f2b(b.x), f2b(b.y), f2b(b.z), f2b(b.w) };
    *((uint4*)dst + i) = *(const uint4*)o;
}

// All four weight matrices -> one contiguous bf16 region:
// rows 0..2047 Wq | 2048..2559 Wk | 2560..3071 Wv | 3072..5119 Wo.
__global__ __launch_bounds__(256) void cvt_weights(
    const float* __restrict__ Wq, const float* __restrict__ Wk,
    const float* __restrict__ Wv, const float* __restrict__ Wo,
    ushort_t* __restrict__ dst)
{
    int i = blockIdx.x * 256 + threadIdx.x;       // 8-elem chunk id
    int row = i >> 8;                              // 256 chunks per 2048-row
    int c8  = i & 255;
    const float* src;
    if      (row < 2048) src = Wq + (size_t)row * 2048;
    else if (row < 2560) src = Wk + (size_t)(row - 2048) * 2048;
    else if (row < 3072) src = Wv + (size_t)(row - 2560) * 2048;
    else                 src = Wo + (size_t)(row - 3072) * 2048;
    float4 a = *((const float4*)src + c8 * 2);
    float4 b = *((const float4*)src + c8 * 2 + 1);
    ushort_t o[8] = { f2b(a.x), f2b(a.y), f2b(a.z), f2b(a.w),
                      f2b(b.x), f2b(b.y), f2b(b.z), f2b(b.w) };
    *((uint4*)dst + i) = *(const uint4*)o;
}

__global__ __launch_bounds__(256) void concat_bias3(
    const float* __restrict__ bq, const float* __restrict__ bk,
    const float* __restrict__ bv, float* __restrict__ dst)
{
    int i = blockIdx.x * 256 + threadIdx.x;
    if (i < 2048) dst[i] = bq[i];
    else if (i < 2560) dst[i] = bk[i - 2048];
    else if (i < 3072) dst[i] = bv[i - 2560];
}

// ---------------------------------------------------------------
// RoPE (cos,sin) table: tab[s*64 + dd] for angle = s * 10000^(-2dd/128).
// Keeps all libm trig OUT of the MFMA epilogue (R6 spill lesson).
// ---------------------------------------------------------------
__global__ __launch_bounds__(256) void rope_tab(float2* __restrict__ tab)
{
    int i = blockIdx.x * 256 + threadIdx.x;   // 0 .. 2048*64-1
    int s = i >> 6, dd = i & 63;
    float invfreq = exp2f(-(float)(2 * dd) * (13.287712379549449f / 128.0f));
    float ang = (float)s * invfreq;
    tab[i] = make_float2(cosf(ang), sinf(ang));
}

// ---------------------------------------------------------------
// QKV GEMM + fused bias + RMSNorm + RoPE (table-based, wave-local rows).
// C[M][3072] = A[M][2048] * W[3072][2048]^T + bias; col tile == head:
// bn 0..15 q-heads (qn_w), 16..19 k-heads (kn_w), 20..23 v (plain).
// 128x128 tile, BK=64, 4 waves in 4x1 layout: wave owns 32 rows x 128 cols
// (acc[2][8]) so the full head-dim of each row is wave-local -> RMSNorm
// via shfl only, no LDS reduce, no extra barrier.
// global_load_lds staging, chunk slot s stored at s^(r&7). XCD swizzle.
// ---------------------------------------------------------------
__global__ __launch_bounds__(256) void gemm_qkv(
    const ushort_t* __restrict__ A, const ushort_t* __restrict__ W,
    const float* __restrict__ bias, ushort_t* __restrict__ C,
    const float* __restrict__ qn_w, const float* __restrict__ kn_w,
    const float2* __restrict__ ropetab, int M, int N, int K)
{
    __shared__ __attribute__((aligned(16))) ushort_t sA[8192];
    __shared__ __attribute__((aligned(16))) ushort_t sB[8192];

    const int tid  = threadIdx.x;
    const int lane = tid & 63;
    const int wave = tid >> 6;
    const int nbn  = N >> 7;

    int nwg = gridDim.x;
    int bid = blockIdx.x;
    int nb  = (nwg & 7) ? bid : ((bid & 7) * (nwg >> 3) + (bid >> 3));
    const int bm = nb / nbn;
    const int bn = nb % nbn;
    const int m0 = bm << 7, n0 = bn << 7;

    f32x4 acc[2][8] = {};

    const int frow = lane & 15;
    const int kg   = lane >> 4;

    const ushort_t* gA[4]; const ushort_t* gB[4];
    ushort_t* lA[4]; ushort_t* lB[4];
#pragma unroll
    for (int j = 0; j < 4; ++j) {
        int t = wave * 4 + j;
        int c = t * 64 + lane;
        int r = c >> 3, s = c & 7;
        int ksrc = s ^ (r & 7);
        gA[j] = A + (size_t)(m0 + r) * K + ksrc * 8;
        gB[j] = W + (size_t)(n0 + r) * K + ksrc * 8;
        lA[j] = sA + t * 512;
        lB[j] = sB + t * 512;
    }

    for (int k0 = 0; k0 < K; k0 += 64) {
        if (k0) __syncthreads();
#pragma unroll
        for (int j = 0; j < 4; ++j) gload_lds16(gA[j] + k0, lA[j]);
#pragma unroll
        for (int j = 0; j < 4; ++j) gload_lds16(gB[j] + k0, lB[j]);
        __syncthreads();

#pragma unroll
        for (int kk = 0; kk < 2; ++kk) {
            bf16x8 af[2];
#pragma unroll
            for (int mi = 0; mi < 2; ++mi) {
                int r = (wave << 5) + (mi << 4) + frow;
                int sl = (kk * 4 + kg) ^ (r & 7);
                af[mi] = *(const bf16x8*)(sA + (r * 8 + sl) * 8);
            }
#pragma unroll
            for (int ni = 0; ni < 8; ++ni) {
                int r = (ni << 4) + frow;
                int sl = (kk * 4 + kg) ^ (r & 7);
                bf16x8 bf = *(const bf16x8*)(sB + (r * 8 + sl) * 8);
                acc[0][ni] = __builtin_amdgcn_mfma_f32_16x16x32_bf16(
                    af[0], bf, acc[0][ni], 0, 0, 0);
                acc[1][ni] = __builtin_amdgcn_mfma_f32_16x16x32_bf16(
                    af[1], bf, acc[1][ni], 0, 0, 0);
            }
        }
    }

    // ---- epilogue: bias, then fused rmsnorm+rope (wave-local, no LDS) ----
    // D frag: col = lane&15, row = (lane>>4)*4 + reg
    const int orow = (lane >> 4) << 2;
    const int ocol = lane & 15;

#pragma unroll
    for (int ni = 0; ni < 8; ++ni) {
        float bvf = bias[n0 + (ni << 4) + ocol];
#pragma unroll
        for (int mi = 0; mi < 2; ++mi)
#pragma unroll
            for (int r = 0; r < 4; ++r)
                acc[mi][ni][r] += bvf;
    }

    if (bn < 20) {                       // q or k head: rmsnorm + rope
        const float* w = (bn < 16) ? qn_w : kn_w;
        float wv[8];
#pragma unroll
        for (int ni = 0; ni < 8; ++ni)
            wv[ni] = w[(ni << 4) + ocol];

#pragma unroll
        for (int mi = 0; mi < 2; ++mi)
#pragma unroll
            for (int r = 0; r < 4; ++r) {
                float p = 0.f;
#pragma unroll
                for (int ni = 0; ni < 8; ++ni)
                    p += acc[mi][ni][r] * acc[mi][ni][r];
#pragma unroll
                for (int off = 1; off <= 8; off <<= 1)
                    p += __shfl_xor(p, off, 64);
                float inv = rsqrtf(p * (1.0f / 128.0f) + 1e-8f);
                int s = (m0 + (wave << 5) + (mi << 4) + orow + r) & 2047;
                const float2* tabs = ropetab + (s << 6);
#pragma unroll
                for (int ni = 0; ni < 8; ++ni) {
                    int d = (ni << 4) + ocol;
                    float xn = acc[mi][ni][r] * inv * wv[ni];
                    float partner = __shfl_xor(xn, 1, 64);
                    float2 cs = tabs[d >> 1];
                    acc[mi][ni][r] = (d & 1) ? (partner * cs.y + xn * cs.x)
                                             : (xn * cs.x - partner * cs.y);
                }
            }
    }

#pragma unroll
    for (int ni = 0; ni < 8; ++ni) {
        int col = n0 + (ni << 4) + ocol;
#pragma unroll
        for (int mi = 0; mi < 2; ++mi)
#pragma unroll
            for (int r = 0; r < 4; ++r) {
                int row = m0 + (wave << 5) + (mi << 4) + orow + r;
                C[(size_t)row * N + col] = f2b(acc[mi][ni][r]);
            }
    }
}

// ---------------------------------------------------------------
// Output GEMM (f32 out): C = A * W^T + bias. R4-verified config:
// 128x128 tile, BK=32, slot = kg^((r>>1)&3), no XCD remap.
// ---------------------------------------------------------------
__global__ __launch_bounds__(256) void gemm_out(
    const ushort_t* __restrict__ A, const ushort_t* __restrict__ W,
    const float* __restrict__ bias, float* __restrict__ C,
    int M, int N, int K)
{
    __shared__ __attribute__((aligned(16))) ushort_t sA[4096];
    __shared__ __attribute__((aligned(16))) ushort_t sB[4096];

    const int tid  = threadIdx.x;
    const int lane = tid & 63;
    const int wave = tid >> 6;
    const int nbn  = N >> 7;
    const int bm   = blockIdx.x / nbn;
    const int bn   = blockIdx.x % nbn;
    const int m0   = bm << 7, n0 = bn << 7;
    const int wm   = wave >> 1, wn = wave & 1;

    f32x4 acc[4][4] = {};

    const int frow = lane & 15;
    const int kg   = lane >> 4;

    const int cc0 = wave * 2, cc1 = wave * 2 + 1;
    const int p0 = cc0 * 64 + lane, p1 = cc1 * 64 + lane;
    const int r0 = p0 >> 2,        r1 = p1 >> 2;
    const int kg0 = (p0 & 3) ^ ((r0 >> 1) & 3);
    const int kg1 = (p1 & 3) ^ ((r1 >> 1) & 3);
    const ushort_t* gA0 = A + (size_t)(m0 + r0) * K + kg0 * 8;
    const ushort_t* gA1 = A + (size_t)(m0 + r1) * K + kg1 * 8;
    const ushort_t* gB0 = W + (size_t)(n0 + r0) * K + kg0 * 8;
    const ushort_t* gB1 = W + (size_t)(n0 + r1) * K + kg1 * 8;
    ushort_t* lA0 = sA + cc0 * 512;
    ushort_t* lA1 = sA + cc1 * 512;
    ushort_t* lB0 = sB + cc0 * 512;
    ushort_t* lB1 = sB + cc1 * 512;

    for (int k0 = 0; k0 < K; k0 += 32) {
        if (k0) __syncthreads();
        gload_lds16(gA0 + k0, lA0);
        gload_lds16(gA1 + k0, lA1);
        gload_lds16(gB0 + k0, lB0);
        gload_lds16(gB1 + k0, lB1);
        __syncthreads();

        bf16x8 af[4], bfr[4];
#pragma unroll
        for (int mi = 0; mi < 4; ++mi) {
            int r = (wm << 6) + (mi << 4) + frow;
            int slot = kg ^ ((r >> 1) & 3);
            af[mi] = *(const bf16x8*)(sA + (((r << 2) | slot) << 3));
        }
#pragma unroll
        for (int ni = 0; ni < 4; ++ni) {
            int r = (wn << 6) + (ni << 4) + frow;
            int slot = kg ^ ((r >> 1) & 3);
            bfr[ni] = *(const bf16x8*)(sB + (((r << 2) | slot) << 3));
        }
#pragma unroll
        for (int mi = 0; mi < 4; ++mi)
#pragma unroll
            for (int ni = 0; ni < 4; ++ni)
                acc[mi][ni] = __builtin_amdgcn_mfma_f32_16x16x32_bf16(
                    af[mi], bfr[ni], acc[mi][ni], 0, 0, 0);
    }

    const int orow = (lane >> 4) << 2;
    const int ocol = lane & 15;
#pragma unroll
    for (int ni = 0; ni < 4; ++ni) {
        int col = n0 + (wn << 6) + (ni << 4) + ocol;
        float bvf = bias[col];
#pragma unroll
        for (int mi = 0; mi < 4; ++mi) {
#pragma unroll
            for (int r = 0; r < 4; ++r) {
                int row = m0 + (wm << 6) + (mi << 4) + orow + r;
                C[(size_t)row * N + col] = acc[mi][ni][r] + bvf;
            }
        }
    }
}

// ---------------------------------------------------------------
// MFMA windowed-causal GQA attention on fused qkv [M][3072].
// Block = 256 thr (4 waves), 64 queries of one (b,h); window union
// [i0-64, i0+63] = 128 keys. K/V at col 2048 / 2560.
// ---------------------------------------------------------------
__global__ __launch_bounds__(256) void attn_mfma(
    const ushort_t* __restrict__ qkv, const float* __restrict__ scp,
    ushort_t* __restrict__ ao)
{
    __shared__ __attribute__((aligned(16))) ushort_t sK[16384];   // K tile, then P(f32)
    __shared__ __attribute__((aligned(16))) ushort_t sVT[16384];  // V^T tile

    const int tid  = threadIdx.x;
    const int lane = tid & 63;
    const int w    = tid >> 6;
    const int c    = lane & 15;
    const int g    = lane >> 4;

    const int blk = blockIdx.x;
    const int qt  = blk & 31;
    const int h   = (blk >> 5) & 15;
    const int b   = blk >> 9;
    const int kvh = h >> 2;
    const int i0  = qt << 6;
    const int jb  = i0 - 64;
    const float scale = scp[0];

    // ---- Q fragments straight from global ----
    bf16x8 aq[4];
    {
        const ushort_t* qp = qkv + ((size_t)(b * 2048 + i0 + w * 16 + c)) * NQKV
                                 + h * 128 + g * 8;
#pragma unroll
        for (int ks = 0; ks < 4; ++ks)
            aq[ks] = *(const bf16x8*)(qp + ks * 32);
    }

    // ---- stage K rows [key][d] ----
    const ushort_t* kvb = qkv + ((size_t)b * 2048) * NQKV + 2048 + kvh * 128;
#pragma unroll
    for (int it = 0; it < 8; ++it) {
        int idx = it * 256 + tid;
        int rr = idx >> 4, cc = idx & 15;
        int j = jb + rr; if (j < 0) j = 0;
        uint4 val = *(const uint4*)(kvb + (size_t)j * NQKV + cc * 8);
        int f2v = (rr & 15) ^ ((rr >> 3) & 15);
        *(uint4*)(sK + (rr * 16 + (cc ^ f2v)) * 8) = val;
    }
    // ---- stage V transposed: VT[d][key] ----
#pragma unroll
    for (int it = 0; it < 4; ++it) {
        int task = it * 256 + tid;
        int pp = task >> 4, d8 = task & 15;
        int j0 = jb + 2 * pp;     if (j0 < 0) j0 = 0;
        int j1 = jb + 2 * pp + 1; if (j1 < 0) j1 = 0;
        ushort_t e0[8]; *(uint4*)e0 = *(const uint4*)(kvb + (size_t)j0 * NQKV + 512 + d8 * 8);
        ushort_t e1[8]; *(uint4*)e1 = *(const uint4*)(kvb + (size_t)j1 * NQKV + 512 + d8 * 8);
        int cc = pp >> 2;
#pragma unroll
        for (int jj = 0; jj < 8; ++jj) {
            int rr = d8 * 8 + jj;
            int f2v = (rr & 15) ^ ((rr >> 3) & 15);
            unsigned int word = (unsigned int)e0[jj] | ((unsigned int)e1[jj] << 16);
            *(unsigned int*)(sVT + (rr * 16 + (cc ^ f2v)) * 8 + (pp & 3) * 2) = word;
        }
    }
    __syncthreads();

    // ---- S = Q K^T ----
    f32x4 s[8] = {};
#pragma unroll
    for (int nt = 0; nt < 8; ++nt) {
        int rr = nt * 16 + c;
        int f2v = (rr & 15) ^ ((rr >> 3) & 15);
#pragma unroll
        for (int ks = 0; ks < 4; ++ks) {
            bf16x8 bk = *(const bf16x8*)(sK + (rr * 16 + ((ks * 4 + g) ^ f2v)) * 8);
            s[nt] = __builtin_amdgcn_mfma_f32_16x16x32_bf16(aq[ks], bk, s[nt], 0, 0, 0);
        }
    }

    // ---- mask + row softmax ----
    float linv[4];
#pragma unroll
    for (int r = 0; r < 4; ++r) {
        int qb = w * 16 + g * 4 + r;
#pragma unroll
        for (int nt = 0; nt < 8; ++nt) {
            int jl = nt * 16 + c;
            bool valid = (jl >= qb) && (jl <= qb + 64) && (i0 + jl >= 64);
            s[nt][r] = valid ? s[nt][r] * scale : -1e30f;
        }
        float m = s[0][r];
#pragma unroll
        for (int nt = 1; nt < 8; ++nt) m = fmaxf(m, s[nt][r]);
#pragma unroll
        for (int off = 1; off <= 8; off <<= 1) m = fmaxf(m, __shfl_xor(m, off, 64));
        float sum = 0.f;
#pragma unroll
        for (int nt = 0; nt < 8; ++nt) {
            float e = __expf(s[nt][r] - m);
            s[nt][r] = e;
            sum += e;
        }
#pragma unroll
        for (int off = 1; off <= 8; off <<= 1) sum += __shfl_xor(sum, off, 64);
        linv[r] = 1.0f / sum;
    }

    // ---- P via LDS ----
    __syncthreads();
    float* Pw = (float*)sK + w * 2048;
#pragma unroll
    for (int nt = 0; nt < 8; ++nt) {
#pragma unroll
        for (int r = 0; r < 4; ++r) {
            int q = g * 4 + r;
            int chunk = nt * 4 + (c >> 2);
            Pw[q * 128 + ((chunk ^ (q & 7)) * 4) + (c & 3)] = s[nt][r];
        }
    }

    // ---- O = P V ----
    f32x4 o[8] = {};
#pragma unroll
    for (int kt = 0; kt < 4; ++kt) {
        float pf[8];
#pragma unroll
        for (int e = 0; e < 2; ++e) {
            int chunk = kt * 8 + g * 2 + e;
            f32x4 v4 = *(const f32x4*)(Pw + c * 128 + ((chunk ^ (c & 7)) * 4));
            pf[e * 4 + 0] = v4[0]; pf[e * 4 + 1] = v4[1];
            pf[e * 4 + 2] = v4[2]; pf[e * 4 + 3] = v4[3];
        }
        ushort_t pb[8];
#pragma unroll
        for (int j = 0; j < 8; ++j) pb[j] = f2b(pf[j]);
        bf16x8 pa = *(const bf16x8*)pb;
#pragma unroll
        for (int dt = 0; dt < 8; ++dt) {
            int rr = dt * 16 + c;
            int f2v = (rr & 15) ^ ((rr >> 3) & 15);
            bf16x8 bv = *(const bf16x8*)(sVT + (rr * 16 + ((kt * 4 + g) ^ f2v)) * 8);
            o[dt] = __builtin_amdgcn_mfma_f32_16x16x32_bf16(pa, bv, o[dt], 0, 0, 0);
        }
    }

    // ---- epilogue ----
    const size_t orow0 = (size_t)(b * 2048 + i0 + w * 16);
#pragma unroll
    for (int dt = 0; dt < 8; ++dt) {
#pragma unroll
        for (int r = 0; r < 4; ++r) {
            int q = g * 4 + r;
            ao[(orow0 + q) * 2048 + h * 128 + dt * 16 + c] = f2b(o[dt][r] * linv[r]);
        }
    }
}

// ---------------------------------------------------------------
extern "C" void kernel_launch(void* const* d_in, const int* in_sizes, int n_in,
                              void* d_out, int out_size, void* d_ws, size_t ws_size,
                              hipStream_t stream)
{
    const float* x   = (const float*)d_in[0];
    const float* Wq  = (const float*)d_in[1];
    const float* bq  = (const float*)d_in[2];
    const float* Wk  = (const float*)d_in[3];
    const float* bk  = (const float*)d_in[4];
    const float* Wv  = (const float*)d_in[5];
    const float* bv  = (const float*)d_in[6];
    const float* Wo  = (const float*)d_in[7];
    const float* bo  = (const float*)d_in[8];
    const float* qnw = (const float*)d_in[9];
    const float* knw = (const float*)d_in[10];
    const float* scp = (const float*)d_in[11];
    float* out = (float*)d_out;

    const int M = BATCH * SEQ;             // 4096
    ushort_t* xb    = (ushort_t*)d_ws;                      // M x 2048 (later: ao)
    ushort_t* qkv0  = xb   + (size_t)M * DMODEL;            // M x 3072
    ushort_t* Wqkvb = qkv0 + (size_t)M * NQKV;              // 3072 x 2048
    ushort_t* Wob   = Wqkvb + (size_t)NQKV * DMODEL;        // 2048 x 2048
    float*    bqkv  = (float*)(Wob + (size_t)DMODEL * DMODEL); // 3072 f32
    float2*   rtab  = (float2*)(bqkv + 3072);               // 2048*64 float2 (1MB)
    ushort_t* ao    = xb;
    (void)ws_size; (void)in_sizes; (void)n_in; (void)out_size;

    cvt_bf16<<<dim3(4096), 256, 0, stream>>>(x, xb, M * DMODEL / 8);
    cvt_weights<<<dim3(5120), 256, 0, stream>>>(Wq, Wk, Wv, Wo, Wqkvb);
    concat_bias3<<<dim3(12), 256, 0, stream>>>(bq, bk, bv, bqkv);
    rope_tab<<<dim3(512), 256, 0, stream>>>(rtab);

    gemm_qkv<<<dim3((M / 128) * (NQKV / 128)), 256, 0, stream>>>(
        xb, Wqkvb, bqkv, qkv0, qnw, knw, rtab, M, NQKV, DMODEL);
    attn_mfma<<<dim3(BATCH * NHEADS * (SEQ / 64)), 256, 0, stream>>>(qkv0, scp, ao);
    gemm_out<<<dim3((M / 128) * (DMODEL / 128)), 256, 0, stream>>>(
        ao, Wob, bo, out, M, DMODEL, DMODEL);
}

// Round 10
// 164.522 us; speedup vs baseline: 1.0177x; 1.0177x over previous
//
#include <hip/hip_runtime.h>

// ---------------- problem constants ----------------
#define BATCH 2
#define SEQ 2048
#define DMODEL 2048
#define NHEADS 16
#define NKV 4
#define DK 128
#define WINH 64   // WINDOW/2
#define NQKV 3072 // 2048 q + 512 k + 512 v

typedef unsigned short ushort_t;
typedef __attribute__((ext_vector_type(8))) __bf16 bf16x8;
typedef __attribute__((ext_vector_type(4))) float f32x4;

__device__ __forceinline__ float b2f(ushort_t u) {
    union { unsigned int i; float f; } v; v.i = ((unsigned int)u) << 16; return v.f;
}
__device__ __forceinline__ ushort_t f2b(float f) {
    union { float f; unsigned int i; } v; v.f = f;
    unsigned int r = v.i + 0x7FFFu + ((v.i >> 16) & 1u);
    return (ushort_t)(r >> 16);
}

// async global->LDS, 16B/lane; LDS dest wave-uniform base + lane*16.
__device__ __forceinline__ void gload_lds16(const ushort_t* g, ushort_t* l) {
    __builtin_amdgcn_global_load_lds(
        (__attribute__((address_space(1))) void*)(void*)const_cast<ushort_t*>(g),
        (__attribute__((address_space(3))) void*)l, 16, 0, 0);
}

// ---------------------------------------------------------------
// f32 -> bf16 cast, 8 elements/thread.
// ---------------------------------------------------------------
__global__ __launch_bounds__(256) void cvt_bf16(
    const float* __restrict__ src, ushort_t* __restrict__ dst, int n8)
{
    int i = blockIdx.x * 256 + threadIdx.x;
    if (i >= n8) return;
    float4 a = *((const float4*)src + i * 2);
    float4 b = *((const float4*)src + i * 2 + 1);
    ushort_t o[8] = { f2b(a.x), f2b(a.y), f2b(a.z), f2b(a.w),
                      f2b(b.x), f2b(b.y), f2b(b.z), f2b(b.w) };
    *((uint4*)dst + i) = *(const uint4*)o;
}

// All four weight matrices -> one contiguous bf16 region:
// rows 0..2047 Wq | 2048..2559 Wk | 2560..3071 Wv | 3072..5119 Wo.
__global__ __launch_bounds__(256) void cvt_weights(
    const float* __restrict__ Wq, const float* __restrict__ Wk,
    const float* __restrict__ Wv, const float* __restrict__ Wo,
    ushort_t* __restrict__ dst)
{
    int i = blockIdx.x * 256 + threadIdx.x;       // 8-elem chunk id
    int row = i >> 8;                              // 256 chunks per 2048-row
    int c8  = i & 255;
    const float* src;
    if      (row < 2048) src = Wq + (size_t)row * 2048;
    else if (row < 2560) src = Wk + (size_t)(row - 2048) * 2048;
    else if (row < 3072) src = Wv + (size_t)(row - 2560) * 2048;
    else                 src = Wo + (size_t)(row - 3072) * 2048;
    float4 a = *((const float4*)src + c8 * 2);
    float4 b = *((const float4*)src + c8 * 2 + 1);
    ushort_t o[8] = { f2b(a.x), f2b(a.y), f2b(a.z), f2b(a.w),
                      f2b(b.x), f2b(b.y), f2b(b.z), f2b(b.w) };
    *((uint4*)dst + i) = *(const uint4*)o;
}

__global__ __launch_bounds__(256) void concat_bias3(
    const float* __restrict__ bq, const float* __restrict__ bk,
    const float* __restrict__ bv, float* __restrict__ dst)
{
    int i = blockIdx.x * 256 + threadIdx.x;
    if (i < 2048) dst[i] = bq[i];
    else if (i < 2560) dst[i] = bk[i - 2048];
    else if (i < 3072) dst[i] = bv[i - 2560];
}

// ---------------------------------------------------------------
// QKV GEMM (R5-verified, 57.5us/896TF): C[M][3072] = A*W^T + bias, bf16 out.
// 128x128 tile, BK=64, 4 waves 2x2, global_load_lds, slot s^(r&7) swizzle,
// bijective XCD swizzle. Plain epilogue (fusion proven net-negative R6-R8).
// ---------------------------------------------------------------
__global__ __launch_bounds__(256) void gemm_qkv(
    const ushort_t* __restrict__ A, const ushort_t* __restrict__ W,
    const float* __restrict__ bias, ushort_t* __restrict__ C,
    int M, int N, int K)
{
    __shared__ __attribute__((aligned(16))) ushort_t sA[8192];
    __shared__ __attribute__((aligned(16))) ushort_t sB[8192];

    const int tid  = threadIdx.x;
    const int lane = tid & 63;
    const int wave = tid >> 6;
    const int nbn  = N >> 7;

    int nwg = gridDim.x;
    int bid = blockIdx.x;
    int nb  = (nwg & 7) ? bid : ((bid & 7) * (nwg >> 3) + (bid >> 3));
    const int bm = nb / nbn;
    const int bn = nb % nbn;
    const int m0 = bm << 7, n0 = bn << 7;
    const int wm = wave >> 1, wn = wave & 1;

    f32x4 acc[4][4] = {};

    const int frow = lane & 15;
    const int kg   = lane >> 4;

    const ushort_t* gA[4]; const ushort_t* gB[4];
    ushort_t* lA[4]; ushort_t* lB[4];
#pragma unroll
    for (int j = 0; j < 4; ++j) {
        int t = wave * 4 + j;
        int c = t * 64 + lane;
        int r = c >> 3, s = c & 7;
        int ksrc = s ^ (r & 7);
        gA[j] = A + (size_t)(m0 + r) * K + ksrc * 8;
        gB[j] = W + (size_t)(n0 + r) * K + ksrc * 8;
        lA[j] = sA + t * 512;
        lB[j] = sB + t * 512;
    }

    for (int k0 = 0; k0 < K; k0 += 64) {
        if (k0) __syncthreads();
#pragma unroll
        for (int j = 0; j < 4; ++j) gload_lds16(gA[j] + k0, lA[j]);
#pragma unroll
        for (int j = 0; j < 4; ++j) gload_lds16(gB[j] + k0, lB[j]);
        __syncthreads();

        bf16x8 af[4][2], bfr[4][2];
#pragma unroll
        for (int mi = 0; mi < 4; ++mi)
#pragma unroll
            for (int kk = 0; kk < 2; ++kk) {
                int r = (wm << 6) + (mi << 4) + frow;
                int sl = (kk * 4 + kg) ^ (r & 7);
                af[mi][kk] = *(const bf16x8*)(sA + (r * 8 + sl) * 8);
            }
#pragma unroll
        for (int ni = 0; ni < 4; ++ni)
#pragma unroll
            for (int kk = 0; kk < 2; ++kk) {
                int r = (wn << 6) + (ni << 4) + frow;
                int sl = (kk * 4 + kg) ^ (r & 7);
                bfr[ni][kk] = *(const bf16x8*)(sB + (r * 8 + sl) * 8);
            }
#pragma unroll
        for (int kk = 0; kk < 2; ++kk)
#pragma unroll
            for (int mi = 0; mi < 4; ++mi)
#pragma unroll
                for (int ni = 0; ni < 4; ++ni)
                    acc[mi][ni] = __builtin_amdgcn_mfma_f32_16x16x32_bf16(
                        af[mi][kk], bfr[ni][kk], acc[mi][ni], 0, 0, 0);
    }

    // D: col = lane&15, row = (lane>>4)*4 + reg  [m89-verified]
    const int orow = (lane >> 4) << 2;
    const int ocol = lane & 15;
#pragma unroll
    for (int ni = 0; ni < 4; ++ni) {
        int col = n0 + (wn << 6) + (ni << 4) + ocol;
        float bvf = bias[col];
#pragma unroll
        for (int mi = 0; mi < 4; ++mi) {
#pragma unroll
            for (int r = 0; r < 4; ++r) {
                int row = m0 + (wm << 6) + (mi << 4) + orow + r;
                C[(size_t)row * N + col] = f2b(acc[mi][ni][r] + bvf);
            }
        }
    }
}

// ---------------------------------------------------------------
// Fused RMSNorm + RoPE, IN-PLACE on qkv [M][3072] (R5-verified).
// Slot hh 0..19: q heads at cols hh*128, k heads at 2048+(hh-16)*128
// (same formula hh*128). v untouched.
// ---------------------------------------------------------------
__global__ __launch_bounds__(128) void rmsrope(
    ushort_t* __restrict__ qkv, const float* __restrict__ qw,
    const float* __restrict__ kw)
{
    const int d   = threadIdx.x;           // 0..127
    const int blk = blockIdx.x;
    const int bs  = blk / 20;
    const int hh  = blk % 20;
    const int s   = bs & 2047;

    ushort_t* p = qkv + (size_t)bs * NQKV + hh * DK;
    const float* w = (hh < NHEADS) ? qw : kw;

    float x  = b2f(p[d]);
    float ss = x * x;
#pragma unroll
    for (int off = 32; off; off >>= 1) ss += __shfl_xor(ss, off, 64);
    float s2 = __shfl_xor(ss, 0, 64);      // both halves hold full sum? no:
    // 128 threads = 2 waves; reduce across waves via LDS
    __shared__ float red[2];
    if ((d & 63) == 0) red[d >> 6] = ss;
    __syncthreads();
    float tot = red[0] + red[1];
    (void)s2;
    float inv = rsqrtf(tot * (1.0f / 128.0f) + 1e-8f);
    float xn  = x * inv * w[d];

    float partner = __shfl_xor(xn, 1, 64);
    float invfreq = exp2f(-(float)(d & ~1) * (13.287712379549449f / 128.0f));
    float angle   = (float)s * invfreq;
    float c = cosf(angle), sn = sinf(angle);
    float o = (d & 1) ? (partner * sn + xn * c) : (xn * c - partner * sn);
    p[d] = f2b(o);
}

// ---------------------------------------------------------------
// Output GEMM (f32 out) with in-block split-K: 512 thr = 8 waves.
// 128x128 tile, BK=64/iter; wave-group g=wave>>2 computes k-half g.
// Group 1 dumps acc to 64KB LDS (union w/ staging), group 0 adds+writes.
// 16 waves/CU at 2 blocks/CU (vs 8 before) -> hides the vmcnt drain.
// ---------------------------------------------------------------
__global__ __launch_bounds__(512) void gemm_out_ks(
    const ushort_t* __restrict__ A, const ushort_t* __restrict__ W,
    const float* __restrict__ bias, float* __restrict__ C,
    int M, int N, int K)
{
    __shared__ __attribute__((aligned(16))) unsigned char smem[65536];
    ushort_t* sA = (ushort_t*)smem;            // 16KB: 128x64 bf16
    ushort_t* sB = (ushort_t*)(smem + 16384);  // 16KB
    float*    red = (float*)smem;              // 64KB after K-loop

    const int tid  = threadIdx.x;
    const int lane = tid & 63;
    const int wave = tid >> 6;                 // 0..7
    const int g    = wave >> 2;                // k-half group
    const int q    = wave & 3;                 // quadrant
    const int wm   = q >> 1, wn = q & 1;
    const int nbn  = N >> 7;

    int nwg = gridDim.x;
    int bid = blockIdx.x;
    int nb  = (nwg & 7) ? bid : ((bid & 7) * (nwg >> 3) + (bid >> 3));
    const int bm = nb / nbn;
    const int bn = nb % nbn;
    const int m0 = bm << 7, n0 = bn << 7;

    f32x4 acc[4][4] = {};

    const int frow = lane & 15;
    const int kg   = lane >> 4;

    // staging: 16 sets of 64x16B per matrix; wave w stages sets {2w, 2w+1}.
    const ushort_t* gA[2]; const ushort_t* gB[2];
    ushort_t* lA[2]; ushort_t* lB[2];
#pragma unroll
    for (int j = 0; j < 2; ++j) {
        int t = wave * 2 + j;
        int c = t * 64 + lane;
        int r = c >> 3, s = c & 7;
        int ksrc = s ^ (r & 7);
        gA[j] = A + (size_t)(m0 + r) * K + ksrc * 8;
        gB[j] = W + (size_t)(n0 + r) * K + ksrc * 8;
        lA[j] = sA + t * 512;
        lB[j] = sB + t * 512;
    }

    for (int k0 = 0; k0 < K; k0 += 64) {
        if (k0) __syncthreads();
#pragma unroll
        for (int j = 0; j < 2; ++j) gload_lds16(gA[j] + k0, lA[j]);
#pragma unroll
        for (int j = 0; j < 2; ++j) gload_lds16(gB[j] + k0, lB[j]);
        __syncthreads();

        bf16x8 af[4], bfr[4];
#pragma unroll
        for (int mi = 0; mi < 4; ++mi) {
            int r = (wm << 6) + (mi << 4) + frow;
            int sl = ((g << 2) + kg) ^ (r & 7);
            af[mi] = *(const bf16x8*)(sA + (r * 8 + sl) * 8);
        }
#pragma unroll
        for (int ni = 0; ni < 4; ++ni) {
            int r = (wn << 6) + (ni << 4) + frow;
            int sl = ((g << 2) + kg) ^ (r & 7);
            bfr[ni] = *(const bf16x8*)(sB + (r * 8 + sl) * 8);
        }
#pragma unroll
        for (int mi = 0; mi < 4; ++mi)
#pragma unroll
            for (int ni = 0; ni < 4; ++ni)
                acc[mi][ni] = __builtin_amdgcn_mfma_f32_16x16x32_bf16(
                    af[mi], bfr[ni], acc[mi][ni], 0, 0, 0);
    }

    // ---- cross-group reduce via LDS (group 1 -> group 0) ----
    __syncthreads();                       // all staging reads done
    if (g == 1) {
#pragma unroll
        for (int mi = 0; mi < 4; ++mi)
#pragma unroll
            for (int ni = 0; ni < 4; ++ni)
                *(f32x4*)(red + q * 4096 + (mi * 4 + ni) * 256 + lane * 4) =
                    acc[mi][ni];
    }
    __syncthreads();

    if (g == 0) {
        const int orow = (lane >> 4) << 2;
        const int ocol = lane & 15;
#pragma unroll
        for (int ni = 0; ni < 4; ++ni) {
            int col = n0 + (wn << 6) + (ni << 4) + ocol;
            float bvf = bias[col];
#pragma unroll
            for (int mi = 0; mi < 4; ++mi) {
                f32x4 other = *(const f32x4*)(red + q * 4096 + (mi * 4 + ni) * 256 + lane * 4);
#pragma unroll
                for (int r = 0; r < 4; ++r) {
                    int row = m0 + (wm << 6) + (mi << 4) + orow + r;
                    C[(size_t)row * N + col] = acc[mi][ni][r] + other[r] + bvf;
                }
            }
        }
    }
}

// ---------------------------------------------------------------
// MFMA windowed-causal GQA attention on fused qkv [M][3072].
// Block = 256 thr (4 waves), 64 queries of one (b,h); window union
// [i0-64, i0+63] = 128 keys. K/V at col 2048 / 2560.
// ---------------------------------------------------------------
__global__ __launch_bounds__(256) void attn_mfma(
    const ushort_t* __restrict__ qkv, const float* __restrict__ scp,
    ushort_t* __restrict__ ao)
{
    __shared__ __attribute__((aligned(16))) ushort_t sK[16384];   // K tile, then P(f32)
    __shared__ __attribute__((aligned(16))) ushort_t sVT[16384];  // V^T tile

    const int tid  = threadIdx.x;
    const int lane = tid & 63;
    const int w    = tid >> 6;
    const int c    = lane & 15;
    const int g    = lane >> 4;

    const int blk = blockIdx.x;
    const int qt  = blk & 31;
    const int h   = (blk >> 5) & 15;
    const int b   = blk >> 9;
    const int kvh = h >> 2;
    const int i0  = qt << 6;
    const int jb  = i0 - 64;
    const float scale = scp[0];

    // ---- Q fragments straight from global ----
    bf16x8 aq[4];
    {
        const ushort_t* qp = qkv + ((size_t)(b * 2048 + i0 + w * 16 + c)) * NQKV
                                 + h * 128 + g * 8;
#pragma unroll
        for (int ks = 0; ks < 4; ++ks)
            aq[ks] = *(const bf16x8*)(qp + ks * 32);
    }

    // ---- stage K rows [key][d] ----
    const ushort_t* kvb = qkv + ((size_t)b * 2048) * NQKV + 2048 + kvh * 128;
#pragma unroll
    for (int it = 0; it < 8; ++it) {
        int idx = it * 256 + tid;
        int rr = idx >> 4, cc = idx & 15;
        int j = jb + rr; if (j < 0) j = 0;
        uint4 val = *(const uint4*)(kvb + (size_t)j * NQKV + cc * 8);
        int f2v = (rr & 15) ^ ((rr >> 3) & 15);
        *(uint4*)(sK + (rr * 16 + (cc ^ f2v)) * 8) = val;
    }
    // ---- stage V transposed: VT[d][key] ----
#pragma unroll
    for (int it = 0; it < 4; ++it) {
        int task = it * 256 + tid;
        int pp = task >> 4, d8 = task & 15;
        int j0 = jb + 2 * pp;     if (j0 < 0) j0 = 0;
        int j1 = jb + 2 * pp + 1; if (j1 < 0) j1 = 0;
        ushort_t e0[8]; *(uint4*)e0 = *(const uint4*)(kvb + (size_t)j0 * NQKV + 512 + d8 * 8);
        ushort_t e1[8]; *(uint4*)e1 = *(const uint4*)(kvb + (size_t)j1 * NQKV + 512 + d8 * 8);
        int cc = pp >> 2;
#pragma unroll
        for (int jj = 0; jj < 8; ++jj) {
            int rr = d8 * 8 + jj;
            int f2v = (rr & 15) ^ ((rr >> 3) & 15);
            unsigned int word = (unsigned int)e0[jj] | ((unsigned int)e1[jj] << 16);
            *(unsigned int*)(sVT + (rr * 16 + (cc ^ f2v)) * 8 + (pp & 3) * 2) = word;
        }
    }
    __syncthreads();

    // ---- S = Q K^T ----
    f32x4 s[8] = {};
#pragma unroll
    for (int nt = 0; nt < 8; ++nt) {
        int rr = nt * 16 + c;
        int f2v = (rr & 15) ^ ((rr >> 3) & 15);
#pragma unroll
        for (int ks = 0; ks < 4; ++ks) {
            bf16x8 bk = *(const bf16x8*)(sK + (rr * 16 + ((ks * 4 + g) ^ f2v)) * 8);
            s[nt] = __builtin_amdgcn_mfma_f32_16x16x32_bf16(aq[ks], bk, s[nt], 0, 0, 0);
        }
    }

    // ---- mask + row softmax ----
    float linv[4];
#pragma unroll
    for (int r = 0; r < 4; ++r) {
        int qb = w * 16 + g * 4 + r;
#pragma unroll
        for (int nt = 0; nt < 8; ++nt) {
            int jl = nt * 16 + c;
            bool valid = (jl >= qb) && (jl <= qb + 64) && (i0 + jl >= 64);
            s[nt][r] = valid ? s[nt][r] * scale : -1e30f;
        }
        float m = s[0][r];
#pragma unroll
        for (int nt = 1; nt < 8; ++nt) m = fmaxf(m, s[nt][r]);
#pragma unroll
        for (int off = 1; off <= 8; off <<= 1) m = fmaxf(m, __shfl_xor(m, off, 64));
        float sum = 0.f;
#pragma unroll
        for (int nt = 0; nt < 8; ++nt) {
            float e = __expf(s[nt][r] - m);
            s[nt][r] = e;
            sum += e;
        }
#pragma unroll
        for (int off = 1; off <= 8; off <<= 1) sum += __shfl_xor(sum, off, 64);
        linv[r] = 1.0f / sum;
    }

    // ---- P via LDS ----
    __syncthreads();
    float* Pw = (float*)sK + w * 2048;
#pragma unroll
    for (int nt = 0; nt < 8; ++nt) {
#pragma unroll
        for (int r = 0; r < 4; ++r) {
            int q = g * 4 + r;
            int chunk = nt * 4 + (c >> 2);
            Pw[q * 128 + ((chunk ^ (q & 7)) * 4) + (c & 3)] = s[nt][r];
        }
    }

    // ---- O = P V ----
    f32x4 o[8] = {};
#pragma unroll
    for (int kt = 0; kt < 4; ++kt) {
        float pf[8];
#pragma unroll
        for (int e = 0; e < 2; ++e) {
            int chunk = kt * 8 + g * 2 + e;
            f32x4 v4 = *(const f32x4*)(Pw + c * 128 + ((chunk ^ (c & 7)) * 4));
            pf[e * 4 + 0] = v4[0]; pf[e * 4 + 1] = v4[1];
            pf[e * 4 + 2] = v4[2]; pf[e * 4 + 3] = v4[3];
        }
        ushort_t pb[8];
#pragma unroll
        for (int j = 0; j < 8; ++j) pb[j] = f2b(pf[j]);
        bf16x8 pa = *(const bf16x8*)pb;
#pragma unroll
        for (int dt = 0; dt < 8; ++dt) {
            int rr = dt * 16 + c;
            int f2v = (rr & 15) ^ ((rr >> 3) & 15);
            bf16x8 bv = *(const bf16x8*)(sVT + (rr * 16 + ((kt * 4 + g) ^ f2v)) * 8);
            o[dt] = __builtin_amdgcn_mfma_f32_16x16x32_bf16(pa, bv, o[dt], 0, 0, 0);
        }
    }

    // ---- epilogue ----
    const size_t orow0 = (size_t)(b * 2048 + i0 + w * 16);
#pragma unroll
    for (int dt = 0; dt < 8; ++dt) {
#pragma unroll
        for (int r = 0; r < 4; ++r) {
            int q = g * 4 + r;
            ao[(orow0 + q) * 2048 + h * 128 + dt * 16 + c] = f2b(o[dt][r] * linv[r]);
        }
    }
}

// ---------------------------------------------------------------
extern "C" void kernel_launch(void* const* d_in, const int* in_sizes, int n_in,
                              void* d_out, int out_size, void* d_ws, size_t ws_size,
                              hipStream_t stream)
{
    const float* x   = (const float*)d_in[0];
    const float* Wq  = (const float*)d_in[1];
    const float* bq  = (const float*)d_in[2];
    const float* Wk  = (const float*)d_in[3];
    const float* bk  = (const float*)d_in[4];
    const float* Wv  = (const float*)d_in[5];
    const float* bv  = (const float*)d_in[6];
    const float* Wo  = (const float*)d_in[7];
    const float* bo  = (const float*)d_in[8];
    const float* qnw = (const float*)d_in[9];
    const float* knw = (const float*)d_in[10];
    const float* scp = (const float*)d_in[11];
    float* out = (float*)d_out;

    const int M = BATCH * SEQ;             // 4096
    ushort_t* xb    = (ushort_t*)d_ws;                      // M x 2048 (later: ao)
    ushort_t* qkv0  = xb   + (size_t)M * DMODEL;            // M x 3072
    ushort_t* Wqkvb = qkv0 + (size_t)M * NQKV;              // 3072 x 2048
    ushort_t* Wob   = Wqkvb + (size_t)NQKV * DMODEL;        // 2048 x 2048
    float*    bqkv  = (float*)(Wob + (size_t)DMODEL * DMODEL); // 3072 f32
    ushort_t* ao    = xb;
    (void)ws_size; (void)in_sizes; (void)n_in; (void)out_size;

    cvt_bf16<<<dim3(4096), 256, 0, stream>>>(x, xb, M * DMODEL / 8);
    cvt_weights<<<dim3(5120), 256, 0, stream>>>(Wq, Wk, Wv, Wo, Wqkvb);
    concat_bias3<<<dim3(12), 256, 0, stream>>>(bq, bk, bv, bqkv);

    gemm_qkv<<<dim3((M / 128) * (NQKV / 128)), 256, 0, stream>>>(
        xb, Wqkvb, bqkv, qkv0, M, NQKV, DMODEL);
    rmsrope<<<dim3(M * (NHEADS + NKV)), 128, 0, stream>>>(qkv0, qnw, knw);
    attn_mfma<<<dim3(BATCH * NHEADS * (SEQ / 64)), 256, 0, stream>>>(qkv0, scp, ao);
    gemm_out_ks<<<dim3((M / 128) * (DMODEL / 128)), 512, 0, stream>>>(
        ao, Wob, bo, out, M, DMODEL, DMODEL);
}

// Round 11
// 139.651 us; speedup vs baseline: 1.1990x; 1.1781x over previous
//
#include <hip/hip_runtime.h>

// ---------------- problem constants ----------------
#define BATCH 2
#define SEQ 2048
#define DMODEL 2048
#define NHEADS 16
#define NKV 4
#define DK 128
#define WINH 64   // WINDOW/2
#define NQKV 3072 // 2048 q + 512 k + 512 v

typedef unsigned short ushort_t;
typedef __attribute__((ext_vector_type(8))) __bf16 bf16x8;
typedef __attribute__((ext_vector_type(4))) float f32x4;

__device__ __forceinline__ float b2f(ushort_t u) {
    union { unsigned int i; float f; } v; v.i = ((unsigned int)u) << 16; return v.f;
}
__device__ __forceinline__ ushort_t f2b(float f) {
    union { float f; unsigned int i; } v; v.f = f;
    unsigned int r = v.i + 0x7FFFu + ((v.i >> 16) & 1u);
    return (ushort_t)(r >> 16);
}

// async global->LDS, 16B/lane; LDS dest wave-uniform base + lane*16.
__device__ __forceinline__ void gload_lds16(const ushort_t* g, ushort_t* l) {
    __builtin_amdgcn_global_load_lds(
        (__attribute__((address_space(1))) void*)(void*)const_cast<ushort_t*>(g),
        (__attribute__((address_space(3))) void*)l, 16, 0, 0);
}

// ---------------------------------------------------------------
// prep: all input conversion in ONE launch (blockIdx ranges).
//  [0,4096)      : x f32 -> bf16 (xb)
//  [4096,9216)   : Wq|Wk|Wv|Wo f32 -> bf16, contiguous (wdst)
//  [9216,9228)   : bias concat bq|bk|bv (bqkv)
//  [9228,9740)   : RoPE (cos,sin) table (rtab)
// ---------------------------------------------------------------
__global__ __launch_bounds__(256) void prep(
    const float* __restrict__ x,  const float* __restrict__ Wq,
    const float* __restrict__ Wk, const float* __restrict__ Wv,
    const float* __restrict__ Wo, const float* __restrict__ bq,
    const float* __restrict__ bk, const float* __restrict__ bv,
    ushort_t* __restrict__ xb, ushort_t* __restrict__ wdst,
    float* __restrict__ bqkv, float2* __restrict__ rtab)
{
    const int blk = blockIdx.x;
    const int tid = threadIdx.x;
    if (blk < 4096) {                               // x cast
        int i = blk * 256 + tid;
        float4 a = *((const float4*)x + i * 2);
        float4 b = *((const float4*)x + i * 2 + 1);
        ushort_t o[8] = { f2b(a.x), f2b(a.y), f2b(a.z), f2b(a.w),
                          f2b(b.x), f2b(b.y), f2b(b.z), f2b(b.w) };
        *((uint4*)xb + i) = *(const uint4*)o;
    } else if (blk < 9216) {                        // weights cast
        int i = (blk - 4096) * 256 + tid;
        int row = i >> 8, c8 = i & 255;
        const float* src;
        if      (row < 2048) src = Wq + (size_t)row * 2048;
        else if (row < 2560) src = Wk + (size_t)(row - 2048) * 2048;
        else if (row < 3072) src = Wv + (size_t)(row - 2560) * 2048;
        else                 src = Wo + (size_t)(row - 3072) * 2048;
        float4 a = *((const float4*)src + c8 * 2);
        float4 b = *((const float4*)src + c8 * 2 + 1);
        ushort_t o[8] = { f2b(a.x), f2b(a.y), f2b(a.z), f2b(a.w),
                          f2b(b.x), f2b(b.y), f2b(b.z), f2b(b.w) };
        *((uint4*)wdst + i) = *(const uint4*)o;
    } else if (blk < 9228) {                        // bias concat
        int i = (blk - 9216) * 256 + tid;
        if (i < 2048) bqkv[i] = bq[i];
        else if (i < 2560) bqkv[i] = bk[i - 2048];
        else if (i < 3072) bqkv[i] = bv[i - 2560];
    } else {                                        // rope table
        int i = (blk - 9228) * 256 + tid;           // 0..131071
        int s = i >> 6, dd = i & 63;
        float invfreq = exp2f(-(float)(2 * dd) * (13.287712379549449f / 128.0f));
        float ang = (float)s * invfreq;
        rtab[i] = make_float2(cosf(ang), sinf(ang));
    }
}

// ---------------------------------------------------------------
// QKV GEMM (R5/R9-verified ~56us): C[M][3072] = A*W^T + bias, bf16 out.
// 128x128 tile, BK=64, 4 waves 2x2, global_load_lds, slot s^(r&7) swizzle,
// bijective XCD swizzle. Plain epilogue (fusion proven net-negative R6-R8).
// ---------------------------------------------------------------
__global__ __launch_bounds__(256) void gemm_qkv(
    const ushort_t* __restrict__ A, const ushort_t* __restrict__ W,
    const float* __restrict__ bias, ushort_t* __restrict__ C,
    int M, int N, int K)
{
    __shared__ __attribute__((aligned(16))) ushort_t sA[8192];
    __shared__ __attribute__((aligned(16))) ushort_t sB[8192];

    const int tid  = threadIdx.x;
    const int lane = tid & 63;
    const int wave = tid >> 6;
    const int nbn  = N >> 7;

    int nwg = gridDim.x;
    int bid = blockIdx.x;
    int nb  = (nwg & 7) ? bid : ((bid & 7) * (nwg >> 3) + (bid >> 3));
    const int bm = nb / nbn;
    const int bn = nb % nbn;
    const int m0 = bm << 7, n0 = bn << 7;
    const int wm = wave >> 1, wn = wave & 1;

    f32x4 acc[4][4] = {};

    const int frow = lane & 15;
    const int kg   = lane >> 4;

    const ushort_t* gA[4]; const ushort_t* gB[4];
    ushort_t* lA[4]; ushort_t* lB[4];
#pragma unroll
    for (int j = 0; j < 4; ++j) {
        int t = wave * 4 + j;
        int c = t * 64 + lane;
        int r = c >> 3, s = c & 7;
        int ksrc = s ^ (r & 7);
        gA[j] = A + (size_t)(m0 + r) * K + ksrc * 8;
        gB[j] = W + (size_t)(n0 + r) * K + ksrc * 8;
        lA[j] = sA + t * 512;
        lB[j] = sB + t * 512;
    }

    for (int k0 = 0; k0 < K; k0 += 64) {
        if (k0) __syncthreads();
#pragma unroll
        for (int j = 0; j < 4; ++j) gload_lds16(gA[j] + k0, lA[j]);
#pragma unroll
        for (int j = 0; j < 4; ++j) gload_lds16(gB[j] + k0, lB[j]);
        __syncthreads();

        bf16x8 af[4][2], bfr[4][2];
#pragma unroll
        for (int mi = 0; mi < 4; ++mi)
#pragma unroll
            for (int kk = 0; kk < 2; ++kk) {
                int r = (wm << 6) + (mi << 4) + frow;
                int sl = (kk * 4 + kg) ^ (r & 7);
                af[mi][kk] = *(const bf16x8*)(sA + (r * 8 + sl) * 8);
            }
#pragma unroll
        for (int ni = 0; ni < 4; ++ni)
#pragma unroll
            for (int kk = 0; kk < 2; ++kk) {
                int r = (wn << 6) + (ni << 4) + frow;
                int sl = (kk * 4 + kg) ^ (r & 7);
                bfr[ni][kk] = *(const bf16x8*)(sB + (r * 8 + sl) * 8);
            }
#pragma unroll
        for (int kk = 0; kk < 2; ++kk)
#pragma unroll
            for (int mi = 0; mi < 4; ++mi)
#pragma unroll
                for (int ni = 0; ni < 4; ++ni)
                    acc[mi][ni] = __builtin_amdgcn_mfma_f32_16x16x32_bf16(
                        af[mi][kk], bfr[ni][kk], acc[mi][ni], 0, 0, 0);
    }

    // D: col = lane&15, row = (lane>>4)*4 + reg  [m89-verified]
    const int orow = (lane >> 4) << 2;
    const int ocol = lane & 15;
#pragma unroll
    for (int ni = 0; ni < 4; ++ni) {
        int col = n0 + (wn << 6) + (ni << 4) + ocol;
        float bvf = bias[col];
#pragma unroll
        for (int mi = 0; mi < 4; ++mi) {
#pragma unroll
            for (int r = 0; r < 4; ++r) {
                int row = m0 + (wm << 6) + (mi << 4) + orow + r;
                C[(size_t)row * N + col] = f2b(acc[mi][ni][r] + bvf);
            }
        }
    }
}

// ---------------------------------------------------------------
// Output GEMM (f32 out) with in-block split-K: 512 thr = 8 waves (R9).
// ---------------------------------------------------------------
__global__ __launch_bounds__(512) void gemm_out_ks(
    const ushort_t* __restrict__ A, const ushort_t* __restrict__ W,
    const float* __restrict__ bias, float* __restrict__ C,
    int M, int N, int K)
{
    __shared__ __attribute__((aligned(16))) unsigned char smem[65536];
    ushort_t* sA = (ushort_t*)smem;            // 16KB: 128x64 bf16
    ushort_t* sB = (ushort_t*)(smem + 16384);  // 16KB
    float*    red = (float*)smem;              // 64KB after K-loop

    const int tid  = threadIdx.x;
    const int lane = tid & 63;
    const int wave = tid >> 6;                 // 0..7
    const int g    = wave >> 2;                // k-half group
    const int q    = wave & 3;                 // quadrant
    const int wm   = q >> 1, wn = q & 1;
    const int nbn  = N >> 7;

    int nwg = gridDim.x;
    int bid = blockIdx.x;
    int nb  = (nwg & 7) ? bid : ((bid & 7) * (nwg >> 3) + (bid >> 3));
    const int bm = nb / nbn;
    const int bn = nb % nbn;
    const int m0 = bm << 7, n0 = bn << 7;

    f32x4 acc[4][4] = {};

    const int frow = lane & 15;
    const int kg   = lane >> 4;

    const ushort_t* gA[2]; const ushort_t* gB[2];
    ushort_t* lA[2]; ushort_t* lB[2];
#pragma unroll
    for (int j = 0; j < 2; ++j) {
        int t = wave * 2 + j;
        int c = t * 64 + lane;
        int r = c >> 3, s = c & 7;
        int ksrc = s ^ (r & 7);
        gA[j] = A + (size_t)(m0 + r) * K + ksrc * 8;
        gB[j] = W + (size_t)(n0 + r) * K + ksrc * 8;
        lA[j] = sA + t * 512;
        lB[j] = sB + t * 512;
    }

    for (int k0 = 0; k0 < K; k0 += 64) {
        if (k0) __syncthreads();
#pragma unroll
        for (int j = 0; j < 2; ++j) gload_lds16(gA[j] + k0, lA[j]);
#pragma unroll
        for (int j = 0; j < 2; ++j) gload_lds16(gB[j] + k0, lB[j]);
        __syncthreads();

        bf16x8 af[4], bfr[4];
#pragma unroll
        for (int mi = 0; mi < 4; ++mi) {
            int r = (wm << 6) + (mi << 4) + frow;
            int sl = ((g << 2) + kg) ^ (r & 7);
            af[mi] = *(const bf16x8*)(sA + (r * 8 + sl) * 8);
        }
#pragma unroll
        for (int ni = 0; ni < 4; ++ni) {
            int r = (wn << 6) + (ni << 4) + frow;
            int sl = ((g << 2) + kg) ^ (r & 7);
            bfr[ni] = *(const bf16x8*)(sB + (r * 8 + sl) * 8);
        }
#pragma unroll
        for (int mi = 0; mi < 4; ++mi)
#pragma unroll
            for (int ni = 0; ni < 4; ++ni)
                acc[mi][ni] = __builtin_amdgcn_mfma_f32_16x16x32_bf16(
                    af[mi], bfr[ni], acc[mi][ni], 0, 0, 0);
    }

    __syncthreads();
    if (g == 1) {
#pragma unroll
        for (int mi = 0; mi < 4; ++mi)
#pragma unroll
            for (int ni = 0; ni < 4; ++ni)
                *(f32x4*)(red + q * 4096 + (mi * 4 + ni) * 256 + lane * 4) =
                    acc[mi][ni];
    }
    __syncthreads();

    if (g == 0) {
        const int orow = (lane >> 4) << 2;
        const int ocol = lane & 15;
#pragma unroll
        for (int ni = 0; ni < 4; ++ni) {
            int col = n0 + (wn << 6) + (ni << 4) + ocol;
            float bvf = bias[col];
#pragma unroll
            for (int mi = 0; mi < 4; ++mi) {
                f32x4 other = *(const f32x4*)(red + q * 4096 + (mi * 4 + ni) * 256 + lane * 4);
#pragma unroll
                for (int r = 0; r < 4; ++r) {
                    int row = m0 + (wm << 6) + (mi << 4) + orow + r;
                    C[(size_t)row * N + col] = acc[mi][ni][r] + other[r] + bvf;
                }
            }
        }
    }
}

// ---------------------------------------------------------------
// MFMA windowed-causal GQA attention WITH fused RMSNorm+RoPE.
// qkv [M][3072] holds RAW projections (no norm applied).
// Q: norm+rope+scale in-register at fragment load (row dims live in
//    4 lanes -> shfl_xor 16,32; rope pairs are in-lane adjacent).
// K: norm+rope during LDS staging (row chunks in 16 consecutive lanes
//    -> shfl_xor 1,2,4,8). V untouched. cos/sin from table.
// ---------------------------------------------------------------
__global__ __launch_bounds__(256) void attn_mfma(
    const ushort_t* __restrict__ qkv, const float* __restrict__ qn_w,
    const float* __restrict__ kn_w, const float* __restrict__ scp,
    const float2* __restrict__ rtab, ushort_t* __restrict__ ao)
{
    __shared__ __attribute__((aligned(16))) ushort_t sK[16384];   // K tile, then P(f32)
    __shared__ __attribute__((aligned(16))) ushort_t sVT[16384];  // V^T tile

    const int tid  = threadIdx.x;
    const int lane = tid & 63;
    const int w    = tid >> 6;
    const int c    = lane & 15;
    const int g    = lane >> 4;

    const int blk = blockIdx.x;
    const int qt  = blk & 31;
    const int h   = (blk >> 5) & 15;
    const int b   = blk >> 9;
    const int kvh = h >> 2;
    const int i0  = qt << 6;
    const int jb  = i0 - 64;
    const float scale = scp[0];

    // ---- Q fragments: load raw, fused rmsnorm + rope + scale ----
    bf16x8 aq[4];
    {
        const int srow = i0 + w * 16 + c;                 // seq position
        const ushort_t* qp = qkv + ((size_t)(b * 2048 + srow)) * NQKV
                                 + h * 128 + g * 8;
        float xv[4][8];
        float ss = 0.f;
#pragma unroll
        for (int ks = 0; ks < 4; ++ks) {
            ushort_t raw[8];
            *(uint4*)raw = *(const uint4*)(qp + ks * 32);
#pragma unroll
            for (int j = 0; j < 8; ++j) {
                float xf = b2f(raw[j]);
                xv[ks][j] = xf;
                ss += xf * xf;
            }
        }
        ss += __shfl_xor(ss, 16, 64);
        ss += __shfl_xor(ss, 32, 64);
        float inv = rsqrtf(ss * (1.0f / 128.0f) + 1e-8f) * scale;
#pragma unroll
        for (int ks = 0; ks < 4; ++ks) {
            ushort_t outb[8];
#pragma unroll
            for (int jj = 0; jj < 4; ++jj) {
                int d = ks * 32 + g * 8 + 2 * jj;
                float2 w2 = *(const float2*)(qn_w + d);
                float x0 = xv[ks][2 * jj]     * inv * w2.x;
                float x1 = xv[ks][2 * jj + 1] * inv * w2.y;
                float2 cs = rtab[(srow << 6) + (d >> 1)];
                outb[2 * jj]     = f2b(x0 * cs.x - x1 * cs.y);
                outb[2 * jj + 1] = f2b(x0 * cs.y + x1 * cs.x);
            }
            aq[ks] = *(const bf16x8*)outb;
        }
    }

    // ---- stage K rows [key][d] with fused rmsnorm + rope ----
    const ushort_t* kvb = qkv + ((size_t)b * 2048) * NQKV + 2048 + kvh * 128;
#pragma unroll
    for (int it = 0; it < 8; ++it) {
        int idx = it * 256 + tid;
        int rr = idx >> 4, cc = idx & 15;
        int j = jb + rr; if (j < 0) j = 0;
        ushort_t raw[8];
        *(uint4*)raw = *(const uint4*)(kvb + (size_t)j * NQKV + cc * 8);
        float xv[8];
        float ss = 0.f;
#pragma unroll
        for (int jj = 0; jj < 8; ++jj) {
            xv[jj] = b2f(raw[jj]);
            ss += xv[jj] * xv[jj];
        }
        ss += __shfl_xor(ss, 1, 64);
        ss += __shfl_xor(ss, 2, 64);
        ss += __shfl_xor(ss, 4, 64);
        ss += __shfl_xor(ss, 8, 64);
        float inv = rsqrtf(ss * (1.0f / 128.0f) + 1e-8f);
        ushort_t outb[8];
#pragma unroll
        for (int jj = 0; jj < 4; ++jj) {
            int d = cc * 8 + 2 * jj;
            float2 w2 = *(const float2*)(kn_w + d);
            float x0 = xv[2 * jj]     * inv * w2.x;
            float x1 = xv[2 * jj + 1] * inv * w2.y;
            float2 cs = rtab[(j << 6) + (d >> 1)];
            outb[2 * jj]     = f2b(x0 * cs.x - x1 * cs.y);
            outb[2 * jj + 1] = f2b(x0 * cs.y + x1 * cs.x);
        }
        int f2v = (rr & 15) ^ ((rr >> 3) & 15);
        *(uint4*)(sK + (rr * 16 + (cc ^ f2v)) * 8) = *(const uint4*)outb;
    }
    // ---- stage V transposed: VT[d][key] (no norm) ----
#pragma unroll
    for (int it = 0; it < 4; ++it) {
        int task = it * 256 + tid;
        int pp = task >> 4, d8 = task & 15;
        int j0 = jb + 2 * pp;     if (j0 < 0) j0 = 0;
        int j1 = jb + 2 * pp + 1; if (j1 < 0) j1 = 0;
        ushort_t e0[8]; *(uint4*)e0 = *(const uint4*)(kvb + (size_t)j0 * NQKV + 512 + d8 * 8);
        ushort_t e1[8]; *(uint4*)e1 = *(const uint4*)(kvb + (size_t)j1 * NQKV + 512 + d8 * 8);
        int cc = pp >> 2;
#pragma unroll
        for (int jj = 0; jj < 8; ++jj) {
            int rr = d8 * 8 + jj;
            int f2v = (rr & 15) ^ ((rr >> 3) & 15);
            unsigned int word = (unsigned int)e0[jj] | ((unsigned int)e1[jj] << 16);
            *(unsigned int*)(sVT + (rr * 16 + (cc ^ f2v)) * 8 + (pp & 3) * 2) = word;
        }
    }
    __syncthreads();

    // ---- S = Q K^T (scale pre-folded into Q) ----
    f32x4 s[8] = {};
#pragma unroll
    for (int nt = 0; nt < 8; ++nt) {
        int rr = nt * 16 + c;
        int f2v = (rr & 15) ^ ((rr >> 3) & 15);
#pragma unroll
        for (int ks = 0; ks < 4; ++ks) {
            bf16x8 bk = *(const bf16x8*)(sK + (rr * 16 + ((ks * 4 + g) ^ f2v)) * 8);
            s[nt] = __builtin_amdgcn_mfma_f32_16x16x32_bf16(aq[ks], bk, s[nt], 0, 0, 0);
        }
    }

    // ---- mask + row softmax ----
    float linv[4];
#pragma unroll
    for (int r = 0; r < 4; ++r) {
        int qb = w * 16 + g * 4 + r;
#pragma unroll
        for (int nt = 0; nt < 8; ++nt) {
            int jl = nt * 16 + c;
            bool valid = (jl >= qb) && (jl <= qb + 64) && (i0 + jl >= 64);
            s[nt][r] = valid ? s[nt][r] : -1e30f;
        }
        float m = s[0][r];
#pragma unroll
        for (int nt = 1; nt < 8; ++nt) m = fmaxf(m, s[nt][r]);
#pragma unroll
        for (int off = 1; off <= 8; off <<= 1) m = fmaxf(m, __shfl_xor(m, off, 64));
        float sum = 0.f;
#pragma unroll
        for (int nt = 0; nt < 8; ++nt) {
            float e = __expf(s[nt][r] - m);
            s[nt][r] = e;
            sum += e;
        }
#pragma unroll
        for (int off = 1; off <= 8; off <<= 1) sum += __shfl_xor(sum, off, 64);
        linv[r] = 1.0f / sum;
    }

    // ---- P via LDS ----
    __syncthreads();
    float* Pw = (float*)sK + w * 2048;
#pragma unroll
    for (int nt = 0; nt < 8; ++nt) {
#pragma unroll
        for (int r = 0; r < 4; ++r) {
            int q = g * 4 + r;
            int chunk = nt * 4 + (c >> 2);
            Pw[q * 128 + ((chunk ^ (q & 7)) * 4) + (c & 3)] = s[nt][r];
        }
    }

    // ---- O = P V ----
    f32x4 o[8] = {};
#pragma unroll
    for (int kt = 0; kt < 4; ++kt) {
        float pf[8];
#pragma unroll
        for (int e = 0; e < 2; ++e) {
            int chunk = kt * 8 + g * 2 + e;
            f32x4 v4 = *(const f32x4*)(Pw + c * 128 + ((chunk ^ (c & 7)) * 4));
            pf[e * 4 + 0] = v4[0]; pf[e * 4 + 1] = v4[1];
            pf[e * 4 + 2] = v4[2]; pf[e * 4 + 3] = v4[3];
        }
        ushort_t pb[8];
#pragma unroll
        for (int j = 0; j < 8; ++j) pb[j] = f2b(pf[j]);
        bf16x8 pa = *(const bf16x8*)pb;
#pragma unroll
        for (int dt = 0; dt < 8; ++dt) {
            int rr = dt * 16 + c;
            int f2v = (rr & 15) ^ ((rr >> 3) & 15);
            bf16x8 bv = *(const bf16x8*)(sVT + (rr * 16 + ((kt * 4 + g) ^ f2v)) * 8);
            o[dt] = __builtin_amdgcn_mfma_f32_16x16x32_bf16(pa, bv, o[dt], 0, 0, 0);
        }
    }

    // ---- epilogue ----
    const size_t orow0 = (size_t)(b * 2048 + i0 + w * 16);
#pragma unroll
    for (int dt = 0; dt < 8; ++dt) {
#pragma unroll
        for (int r = 0; r < 4; ++r) {
            int q = g * 4 + r;
            ao[(orow0 + q) * 2048 + h * 128 + dt * 16 + c] = f2b(o[dt][r] * linv[r]);
        }
    }
}

// ---------------------------------------------------------------
extern "C" void kernel_launch(void* const* d_in, const int* in_sizes, int n_in,
                              void* d_out, int out_size, void* d_ws, size_t ws_size,
                              hipStream_t stream)
{
    const float* x   = (const float*)d_in[0];
    const float* Wq  = (const float*)d_in[1];
    const float* bq  = (const float*)d_in[2];
    const float* Wk  = (const float*)d_in[3];
    const float* bk  = (const float*)d_in[4];
    const float* Wv  = (const float*)d_in[5];
    const float* bv  = (const float*)d_in[6];
    const float* Wo  = (const float*)d_in[7];
    const float* bo  = (const float*)d_in[8];
    const float* qnw = (const float*)d_in[9];
    const float* knw = (const float*)d_in[10];
    const float* scp = (const float*)d_in[11];
    float* out = (float*)d_out;

    const int M = BATCH * SEQ;             // 4096
    ushort_t* xb    = (ushort_t*)d_ws;                      // M x 2048 (later: ao)
    ushort_t* qkv0  = xb   + (size_t)M * DMODEL;            // M x 3072 (raw)
    ushort_t* Wqkvb = qkv0 + (size_t)M * NQKV;              // 3072 x 2048
    ushort_t* Wob   = Wqkvb + (size_t)NQKV * DMODEL;        // 2048 x 2048
    float*    bqkv  = (float*)(Wob + (size_t)DMODEL * DMODEL); // 3072 f32
    float2*   rtab  = (float2*)(bqkv + 3072);               // 2048*64 float2 (1MB)
    ushort_t* ao    = xb;
    (void)ws_size; (void)in_sizes; (void)n_in; (void)out_size;

    prep<<<dim3(9740), 256, 0, stream>>>(x, Wq, Wk, Wv, Wo, bq, bk, bv,
                                         xb, Wqkvb, bqkv, rtab);
    gemm_qkv<<<dim3((M / 128) * (NQKV / 128)), 256, 0, stream>>>(
        xb, Wqkvb, bqkv, qkv0, M, NQKV, DMODEL);
    attn_mfma<<<dim3(BATCH * NHEADS * (SEQ / 64)), 256, 0, stream>>>(
        qkv0, qnw, knw, scp, rtab, ao);
    gemm_out_ks<<<dim3((M / 128) * (DMODEL / 128)), 512, 0, stream>>>(
        ao, Wob, bo, out, M, DMODEL, DMODEL);
}

// Round 12
// 139.593 us; speedup vs baseline: 1.1995x; 1.0004x over previous
//
#include <hip/hip_runtime.h>

// ---------------- problem constants ----------------
#define BATCH 2
#define SEQ 2048
#define DMODEL 2048
#define NHEADS 16
#define NKV 4
#define DK 128
#define WINH 64   // WINDOW/2
#define NQKV 3072 // 2048 q + 512 k + 512 v

typedef unsigned short ushort_t;
typedef __attribute__((ext_vector_type(8))) __bf16 bf16x8;
typedef __attribute__((ext_vector_type(4))) float f32x4;

__device__ __forceinline__ float b2f(ushort_t u) {
    union { unsigned int i; float f; } v; v.i = ((unsigned int)u) << 16; return v.f;
}
__device__ __forceinline__ ushort_t f2b(float f) {
    union { float f; unsigned int i; } v; v.f = f;
    unsigned int r = v.i + 0x7FFFu + ((v.i >> 16) & 1u);
    return (ushort_t)(r >> 16);
}

// async global->LDS, 16B/lane; LDS dest wave-uniform base + lane*16.
__device__ __forceinline__ void gload_lds16(const ushort_t* g, ushort_t* l) {
    __builtin_amdgcn_global_load_lds(
        (__attribute__((address_space(1))) void*)(void*)const_cast<ushort_t*>(g),
        (__attribute__((address_space(3))) void*)l, 16, 0, 0);
}

// ---------------------------------------------------------------
// prep: all input conversion in ONE launch (blockIdx ranges).
//  [0,4096)      : x f32 -> bf16 (xb)
//  [4096,9216)   : Wq|Wk|Wv|Wo f32 -> bf16, contiguous (wdst)
//  [9216,9228)   : bias concat bq|bk|bv (bqkv)
//  [9228,9740)   : RoPE (cos,sin) table (rtab)
// ---------------------------------------------------------------
__global__ __launch_bounds__(256) void prep(
    const float* __restrict__ x,  const float* __restrict__ Wq,
    const float* __restrict__ Wk, const float* __restrict__ Wv,
    const float* __restrict__ Wo, const float* __restrict__ bq,
    const float* __restrict__ bk, const float* __restrict__ bv,
    ushort_t* __restrict__ xb, ushort_t* __restrict__ wdst,
    float* __restrict__ bqkv, float2* __restrict__ rtab)
{
    const int blk = blockIdx.x;
    const int tid = threadIdx.x;
    if (blk < 4096) {                               // x cast
        int i = blk * 256 + tid;
        float4 a = *((const float4*)x + i * 2);
        float4 b = *((const float4*)x + i * 2 + 1);
        ushort_t o[8] = { f2b(a.x), f2b(a.y), f2b(a.z), f2b(a.w),
                          f2b(b.x), f2b(b.y), f2b(b.z), f2b(b.w) };
        *((uint4*)xb + i) = *(const uint4*)o;
    } else if (blk < 9216) {                        // weights cast
        int i = (blk - 4096) * 256 + tid;
        int row = i >> 8, c8 = i & 255;
        const float* src;
        if      (row < 2048) src = Wq + (size_t)row * 2048;
        else if (row < 2560) src = Wk + (size_t)(row - 2048) * 2048;
        else if (row < 3072) src = Wv + (size_t)(row - 2560) * 2048;
        else                 src = Wo + (size_t)(row - 3072) * 2048;
        float4 a = *((const float4*)src + c8 * 2);
        float4 b = *((const float4*)src + c8 * 2 + 1);
        ushort_t o[8] = { f2b(a.x), f2b(a.y), f2b(a.z), f2b(a.w),
                          f2b(b.x), f2b(b.y), f2b(b.z), f2b(b.w) };
        *((uint4*)wdst + i) = *(const uint4*)o;
    } else if (blk < 9228) {                        // bias concat
        int i = (blk - 9216) * 256 + tid;
        if (i < 2048) bqkv[i] = bq[i];
        else if (i < 2560) bqkv[i] = bk[i - 2048];
        else if (i < 3072) bqkv[i] = bv[i - 2560];
    } else {                                        // rope table
        int i = (blk - 9228) * 256 + tid;           // 0..131071
        int s = i >> 6, dd = i & 63;
        float invfreq = exp2f(-(float)(2 * dd) * (13.287712379549449f / 128.0f));
        float ang = (float)s * invfreq;
        rtab[i] = make_float2(cosf(ang), sinf(ang));
    }
}

// ---------------------------------------------------------------
// QKV GEMM, 256x256 tile: C[M][3072] = A*W^T + bias, bf16 out.
// 512 thr = 8 waves (2M x 4N); per-wave output 128x64 (acc[8][4]).
// BK=64; LDS = 2 dbuf x (A 32KB + B 32KB) = 128KB (dynamic).
// Pipeline: stage(buf^1, t+1) issued at iteration START, one
// __syncthreads per K-tile at the END -> its vmcnt(0) waits on loads
// issued a full compute-tile earlier (mostly landed). Conflict-free
// chunk swizzle slot = s^(r&7) (0 bank conflicts, session-verified).
// Bijective XCD swizzle (grid 192 % 8 == 0).
// ---------------------------------------------------------------
__global__ __launch_bounds__(512) void gemm_qkv_256(
    const ushort_t* __restrict__ A, const ushort_t* __restrict__ W,
    const float* __restrict__ bias, ushort_t* __restrict__ C,
    int M, int N, int K)
{
    extern __shared__ __attribute__((aligned(16))) ushort_t smem[];
    // layout (elements): sA[buf] = smem + buf*16384 ; sB[buf] = smem + 32768 + buf*16384

    const int tid  = threadIdx.x;
    const int lane = tid & 63;
    const int wave = tid >> 6;          // 0..7
    const int wm   = wave >> 2;         // 0..1 -> rows wm*128..+128
    const int wn   = wave & 3;          // 0..3 -> cols wn*64..+64
    const int nbn  = N >> 8;

    int nwg = gridDim.x;
    int bid = blockIdx.x;
    int nb  = (nwg & 7) ? bid : ((bid & 7) * (nwg >> 3) + (bid >> 3));
    const int bm = nb / nbn;
    const int bn = nb % nbn;
    const int m0 = bm << 8, n0 = bn << 8;

    f32x4 acc[8][4] = {};

    const int frow = lane & 15;
    const int kg   = lane >> 4;

    // staging: per matrix 2048 chunks of 16B (256 rows x 8 slots);
    // 4 rounds x 8 waves x 64 lanes. chunk c: r=c>>3, store slot c&7,
    // source k-slot = (c&7)^(r&7). LDS dest linear (wave-uniform + lane*16).
    const ushort_t* gA[4]; const ushort_t* gB[4];
    int lofs[4];
#pragma unroll
    for (int j = 0; j < 4; ++j) {
        int c = j * 512 + wave * 64 + lane;
        int r = c >> 3, s = c & 7;
        int ksrc = s ^ (r & 7);
        gA[j] = A + (size_t)(m0 + r) * K + ksrc * 8;
        gB[j] = W + (size_t)(n0 + r) * K + ksrc * 8;
        lofs[j] = (j * 512 + wave * 64) * 8;        // element offset of chunk base
    }

    const int nt = K >> 6;                          // 32 K-tiles
    // prologue: stage tile 0 into buf 0
#pragma unroll
    for (int j = 0; j < 4; ++j) gload_lds16(gA[j], smem + lofs[j]);
#pragma unroll
    for (int j = 0; j < 4; ++j) gload_lds16(gB[j], smem + 32768 + lofs[j]);
    __syncthreads();

    for (int t = 0; t < nt; ++t) {
        const int cur = t & 1;
        // issue next-tile prefetch FIRST (drained by the syncthreads below,
        // a full compute-tile later)
        if (t + 1 < nt) {
            const int nxt = cur ^ 1;
            const int ko = (t + 1) << 6;
#pragma unroll
            for (int j = 0; j < 4; ++j)
                gload_lds16(gA[j] + ko, smem + nxt * 16384 + lofs[j]);
#pragma unroll
            for (int j = 0; j < 4; ++j)
                gload_lds16(gB[j] + ko, smem + 32768 + nxt * 16384 + lofs[j]);
        }

        const ushort_t* bufA = smem + cur * 16384;
        const ushort_t* bufB = smem + 32768 + cur * 16384;
#pragma unroll
        for (int kk = 0; kk < 2; ++kk) {
            bf16x8 af[8], bf[4];
#pragma unroll
            for (int mf = 0; mf < 8; ++mf) {
                int r = wm * 128 + mf * 16 + frow;
                int pos = r * 8 + ((kk * 4 + kg) ^ (r & 7));
                af[mf] = *(const bf16x8*)(bufA + pos * 8);
            }
#pragma unroll
            for (int nf = 0; nf < 4; ++nf) {
                int r = wn * 64 + nf * 16 + frow;
                int pos = r * 8 + ((kk * 4 + kg) ^ (r & 7));
                bf[nf] = *(const bf16x8*)(bufB + pos * 8);
            }
#pragma unroll
            for (int mf = 0; mf < 8; ++mf)
#pragma unroll
                for (int nf = 0; nf < 4; ++nf)
                    acc[mf][nf] = __builtin_amdgcn_mfma_f32_16x16x32_bf16(
                        af[mf], bf[nf], acc[mf][nf], 0, 0, 0);
        }
        __syncthreads();   // drains: this tile's ds_reads + next tile's gloads
    }

    // D: col = lane&15, row = (lane>>4)*4 + reg  [m89-verified]
    const int orow = (lane >> 4) << 2;
    const int ocol = lane & 15;
#pragma unroll
    for (int nf = 0; nf < 4; ++nf) {
        int col = n0 + wn * 64 + nf * 16 + ocol;
        float bvf = bias[col];
#pragma unroll
        for (int mf = 0; mf < 8; ++mf) {
#pragma unroll
            for (int r = 0; r < 4; ++r) {
                int row = m0 + wm * 128 + mf * 16 + orow + r;
                C[(size_t)row * N + col] = f2b(acc[mf][nf][r] + bvf);
            }
        }
    }
}

// ---------------------------------------------------------------
// Output GEMM (f32 out) with in-block split-K: 512 thr = 8 waves (R9).
// ---------------------------------------------------------------
__global__ __launch_bounds__(512) void gemm_out_ks(
    const ushort_t* __restrict__ A, const ushort_t* __restrict__ W,
    const float* __restrict__ bias, float* __restrict__ C,
    int M, int N, int K)
{
    __shared__ __attribute__((aligned(16))) unsigned char smem[65536];
    ushort_t* sA = (ushort_t*)smem;            // 16KB: 128x64 bf16
    ushort_t* sB = (ushort_t*)(smem + 16384);  // 16KB
    float*    red = (float*)smem;              // 64KB after K-loop

    const int tid  = threadIdx.x;
    const int lane = tid & 63;
    const int wave = tid >> 6;                 // 0..7
    const int g    = wave >> 2;                // k-half group
    const int q    = wave & 3;                 // quadrant
    const int wm   = q >> 1, wn = q & 1;
    const int nbn  = N >> 7;

    int nwg = gridDim.x;
    int bid = blockIdx.x;
    int nb  = (nwg & 7) ? bid : ((bid & 7) * (nwg >> 3) + (bid >> 3));
    const int bm = nb / nbn;
    const int bn = nb % nbn;
    const int m0 = bm << 7, n0 = bn << 7;

    f32x4 acc[4][4] = {};

    const int frow = lane & 15;
    const int kg   = lane >> 4;

    const ushort_t* gA[2]; const ushort_t* gB[2];
    ushort_t* lA[2]; ushort_t* lB[2];
#pragma unroll
    for (int j = 0; j < 2; ++j) {
        int t = wave * 2 + j;
        int c = t * 64 + lane;
        int r = c >> 3, s = c & 7;
        int ksrc = s ^ (r & 7);
        gA[j] = A + (size_t)(m0 + r) * K + ksrc * 8;
        gB[j] = W + (size_t)(n0 + r) * K + ksrc * 8;
        lA[j] = sA + t * 512;
        lB[j] = sB + t * 512;
    }

    for (int k0 = 0; k0 < K; k0 += 64) {
        if (k0) __syncthreads();
#pragma unroll
        for (int j = 0; j < 2; ++j) gload_lds16(gA[j] + k0, lA[j]);
#pragma unroll
        for (int j = 0; j < 2; ++j) gload_lds16(gB[j] + k0, lB[j]);
        __syncthreads();

        bf16x8 af[4], bfr[4];
#pragma unroll
        for (int mi = 0; mi < 4; ++mi) {
            int r = (wm << 6) + (mi << 4) + frow;
            int sl = ((g << 2) + kg) ^ (r & 7);
            af[mi] = *(const bf16x8*)(sA + (r * 8 + sl) * 8);
        }
#pragma unroll
        for (int ni = 0; ni < 4; ++ni) {
            int r = (wn << 6) + (ni << 4) + frow;
            int sl = ((g << 2) + kg) ^ (r & 7);
            bfr[ni] = *(const bf16x8*)(sB + (r * 8 + sl) * 8);
        }
#pragma unroll
        for (int mi = 0; mi < 4; ++mi)
#pragma unroll
            for (int ni = 0; ni < 4; ++ni)
                acc[mi][ni] = __builtin_amdgcn_mfma_f32_16x16x32_bf16(
                    af[mi], bfr[ni], acc[mi][ni], 0, 0, 0);
    }

    __syncthreads();
    if (g == 1) {
#pragma unroll
        for (int mi = 0; mi < 4; ++mi)
#pragma unroll
            for (int ni = 0; ni < 4; ++ni)
                *(f32x4*)(red + q * 4096 + (mi * 4 + ni) * 256 + lane * 4) =
                    acc[mi][ni];
    }
    __syncthreads();

    if (g == 0) {
        const int orow = (lane >> 4) << 2;
        const int ocol = lane & 15;
#pragma unroll
        for (int ni = 0; ni < 4; ++ni) {
            int col = n0 + (wn << 6) + (ni << 4) + ocol;
            float bvf = bias[col];
#pragma unroll
            for (int mi = 0; mi < 4; ++mi) {
                f32x4 other = *(const f32x4*)(red + q * 4096 + (mi * 4 + ni) * 256 + lane * 4);
#pragma unroll
                for (int r = 0; r < 4; ++r) {
                    int row = m0 + (wm << 6) + (mi << 4) + orow + r;
                    C[(size_t)row * N + col] = acc[mi][ni][r] + other[r] + bvf;
                }
            }
        }
    }
}

// ---------------------------------------------------------------
// MFMA windowed-causal GQA attention WITH fused RMSNorm+RoPE (R10).
// ---------------------------------------------------------------
__global__ __launch_bounds__(256) void attn_mfma(
    const ushort_t* __restrict__ qkv, const float* __restrict__ qn_w,
    const float* __restrict__ kn_w, const float* __restrict__ scp,
    const float2* __restrict__ rtab, ushort_t* __restrict__ ao)
{
    __shared__ __attribute__((aligned(16))) ushort_t sK[16384];   // K tile, then P(f32)
    __shared__ __attribute__((aligned(16))) ushort_t sVT[16384];  // V^T tile

    const int tid  = threadIdx.x;
    const int lane = tid & 63;
    const int w    = tid >> 6;
    const int c    = lane & 15;
    const int g    = lane >> 4;

    const int blk = blockIdx.x;
    const int qt  = blk & 31;
    const int h   = (blk >> 5) & 15;
    const int b   = blk >> 9;
    const int kvh = h >> 2;
    const int i0  = qt << 6;
    const int jb  = i0 - 64;
    const float scale = scp[0];

    // ---- Q fragments: load raw, fused rmsnorm + rope + scale ----
    bf16x8 aq[4];
    {
        const int srow = i0 + w * 16 + c;                 // seq position
        const ushort_t* qp = qkv + ((size_t)(b * 2048 + srow)) * NQKV
                                 + h * 128 + g * 8;
        float xv[4][8];
        float ss = 0.f;
#pragma unroll
        for (int ks = 0; ks < 4; ++ks) {
            ushort_t raw[8];
            *(uint4*)raw = *(const uint4*)(qp + ks * 32);
#pragma unroll
            for (int j = 0; j < 8; ++j) {
                float xf = b2f(raw[j]);
                xv[ks][j] = xf;
                ss += xf * xf;
            }
        }
        ss += __shfl_xor(ss, 16, 64);
        ss += __shfl_xor(ss, 32, 64);
        float inv = rsqrtf(ss * (1.0f / 128.0f) + 1e-8f) * scale;
#pragma unroll
        for (int ks = 0; ks < 4; ++ks) {
            ushort_t outb[8];
#pragma unroll
            for (int jj = 0; jj < 4; ++jj) {
                int d = ks * 32 + g * 8 + 2 * jj;
                float2 w2 = *(const float2*)(qn_w + d);
                float x0 = xv[ks][2 * jj]     * inv * w2.x;
                float x1 = xv[ks][2 * jj + 1] * inv * w2.y;
                float2 cs = rtab[(srow << 6) + (d >> 1)];
                outb[2 * jj]     = f2b(x0 * cs.x - x1 * cs.y);
                outb[2 * jj + 1] = f2b(x0 * cs.y + x1 * cs.x);
            }
            aq[ks] = *(const bf16x8*)outb;
        }
    }

    // ---- stage K rows [key][d] with fused rmsnorm + rope ----
    const ushort_t* kvb = qkv + ((size_t)b * 2048) * NQKV + 2048 + kvh * 128;
#pragma unroll
    for (int it = 0; it < 8; ++it) {
        int idx = it * 256 + tid;
        int rr = idx >> 4, cc = idx & 15;
        int j = jb + rr; if (j < 0) j = 0;
        ushort_t raw[8];
        *(uint4*)raw = *(const uint4*)(kvb + (size_t)j * NQKV + cc * 8);
        float xv[8];
        float ss = 0.f;
#pragma unroll
        for (int jj = 0; jj < 8; ++jj) {
            xv[jj] = b2f(raw[jj]);
            ss += xv[jj] * xv[jj];
        }
        ss += __shfl_xor(ss, 1, 64);
        ss += __shfl_xor(ss, 2, 64);
        ss += __shfl_xor(ss, 4, 64);
        ss += __shfl_xor(ss, 8, 64);
        float inv = rsqrtf(ss * (1.0f / 128.0f) + 1e-8f);
        ushort_t outb[8];
#pragma unroll
        for (int jj = 0; jj < 4; ++jj) {
            int d = cc * 8 + 2 * jj;
            float2 w2 = *(const float2*)(kn_w + d);
            float x0 = xv[2 * jj]     * inv * w2.x;
            float x1 = xv[2 * jj + 1] * inv * w2.y;
            float2 cs = rtab[(j << 6) + (d >> 1)];
            outb[2 * jj]     = f2b(x0 * cs.x - x1 * cs.y);
            outb[2 * jj + 1] = f2b(x0 * cs.y + x1 * cs.x);
        }
        int f2v = (rr & 15) ^ ((rr >> 3) & 15);
        *(uint4*)(sK + (rr * 16 + (cc ^ f2v)) * 8) = *(const uint4*)outb;
    }
    // ---- stage V transposed: VT[d][key] (no norm) ----
#pragma unroll
    for (int it = 0; it < 4; ++it) {
        int task = it * 256 + tid;
        int pp = task >> 4, d8 = task & 15;
        int j0 = jb + 2 * pp;     if (j0 < 0) j0 = 0;
        int j1 = jb + 2 * pp + 1; if (j1 < 0) j1 = 0;
        ushort_t e0[8]; *(uint4*)e0 = *(const uint4*)(kvb + (size_t)j0 * NQKV + 512 + d8 * 8);
        ushort_t e1[8]; *(uint4*)e1 = *(const uint4*)(kvb + (size_t)j1 * NQKV + 512 + d8 * 8);
        int cc = pp >> 2;
#pragma unroll
        for (int jj = 0; jj < 8; ++jj) {
            int rr = d8 * 8 + jj;
            int f2v = (rr & 15) ^ ((rr >> 3) & 15);
            unsigned int word = (unsigned int)e0[jj] | ((unsigned int)e1[jj] << 16);
            *(unsigned int*)(sVT + (rr * 16 + (cc ^ f2v)) * 8 + (pp & 3) * 2) = word;
        }
    }
    __syncthreads();

    // ---- S = Q K^T (scale pre-folded into Q) ----
    f32x4 s[8] = {};
#pragma unroll
    for (int nt = 0; nt < 8; ++nt) {
        int rr = nt * 16 + c;
        int f2v = (rr & 15) ^ ((rr >> 3) & 15);
#pragma unroll
        for (int ks = 0; ks < 4; ++ks) {
            bf16x8 bk = *(const bf16x8*)(sK + (rr * 16 + ((ks * 4 + g) ^ f2v)) * 8);
            s[nt] = __builtin_amdgcn_mfma_f32_16x16x32_bf16(aq[ks], bk, s[nt], 0, 0, 0);
        }
    }

    // ---- mask + row softmax ----
    float linv[4];
#pragma unroll
    for (int r = 0; r < 4; ++r) {
        int qb = w * 16 + g * 4 + r;
#pragma unroll
        for (int nt = 0; nt < 8; ++nt) {
            int jl = nt * 16 + c;
            bool valid = (jl >= qb) && (jl <= qb + 64) && (i0 + jl >= 64);
            s[nt][r] = valid ? s[nt][r] : -1e30f;
        }
        float m = s[0][r];
#pragma unroll
        for (int nt = 1; nt < 8; ++nt) m = fmaxf(m, s[nt][r]);
#pragma unroll
        for (int off = 1; off <= 8; off <<= 1) m = fmaxf(m, __shfl_xor(m, off, 64));
        float sum = 0.f;
#pragma unroll
        for (int nt = 0; nt < 8; ++nt) {
            float e = __expf(s[nt][r] - m);
            s[nt][r] = e;
            sum += e;
        }
#pragma unroll
        for (int off = 1; off <= 8; off <<= 1) sum += __shfl_xor(sum, off, 64);
        linv[r] = 1.0f / sum;
    }

    // ---- P via LDS ----
    __syncthreads();
    float* Pw = (float*)sK + w * 2048;
#pragma unroll
    for (int nt = 0; nt < 8; ++nt) {
#pragma unroll
        for (int r = 0; r < 4; ++r) {
            int q = g * 4 + r;
            int chunk = nt * 4 + (c >> 2);
            Pw[q * 128 + ((chunk ^ (q & 7)) * 4) + (c & 3)] = s[nt][r];
        }
    }

    // ---- O = P V ----
    f32x4 o[8] = {};
#pragma unroll
    for (int kt = 0; kt < 4; ++kt) {
        float pf[8];
#pragma unroll
        for (int e = 0; e < 2; ++e) {
            int chunk = kt * 8 + g * 2 + e;
            f32x4 v4 = *(const f32x4*)(Pw + c * 128 + ((chunk ^ (c & 7)) * 4));
            pf[e * 4 + 0] = v4[0]; pf[e * 4 + 1] = v4[1];
            pf[e * 4 + 2] = v4[2]; pf[e * 4 + 3] = v4[3];
        }
        ushort_t pb[8];
#pragma unroll
        for (int j = 0; j < 8; ++j) pb[j] = f2b(pf[j]);
        bf16x8 pa = *(const bf16x8*)pb;
#pragma unroll
        for (int dt = 0; dt < 8; ++dt) {
            int rr = dt * 16 + c;
            int f2v = (rr & 15) ^ ((rr >> 3) & 15);
            bf16x8 bv = *(const bf16x8*)(sVT + (rr * 16 + ((kt * 4 + g) ^ f2v)) * 8);
            o[dt] = __builtin_amdgcn_mfma_f32_16x16x32_bf16(pa, bv, o[dt], 0, 0, 0);
        }
    }

    // ---- epilogue ----
    const size_t orow0 = (size_t)(b * 2048 + i0 + w * 16);
#pragma unroll
    for (int dt = 0; dt < 8; ++dt) {
#pragma unroll
        for (int r = 0; r < 4; ++r) {
            int q = g * 4 + r;
            ao[(orow0 + q) * 2048 + h * 128 + dt * 16 + c] = f2b(o[dt][r] * linv[r]);
        }
    }
}

// ---------------------------------------------------------------
extern "C" void kernel_launch(void* const* d_in, const int* in_sizes, int n_in,
                              void* d_out, int out_size, void* d_ws, size_t ws_size,
                              hipStream_t stream)
{
    const float* x   = (const float*)d_in[0];
    const float* Wq  = (const float*)d_in[1];
    const float* bq  = (const float*)d_in[2];
    const float* Wk  = (const float*)d_in[3];
    const float* bk  = (const float*)d_in[4];
    const float* Wv  = (const float*)d_in[5];
    const float* bv  = (const float*)d_in[6];
    const float* Wo  = (const float*)d_in[7];
    const float* bo  = (const float*)d_in[8];
    const float* qnw = (const float*)d_in[9];
    const float* knw = (const float*)d_in[10];
    const float* scp = (const float*)d_in[11];
    float* out = (float*)d_out;

    const int M = BATCH * SEQ;             // 4096
    ushort_t* xb    = (ushort_t*)d_ws;                      // M x 2048 (later: ao)
    ushort_t* qkv0  = xb   + (size_t)M * DMODEL;            // M x 3072 (raw)
    ushort_t* Wqkvb = qkv0 + (size_t)M * NQKV;              // 3072 x 2048
    ushort_t* Wob   = Wqkvb + (size_t)NQKV * DMODEL;        // 2048 x 2048
    float*    bqkv  = (float*)(Wob + (size_t)DMODEL * DMODEL); // 3072 f32
    float2*   rtab  = (float2*)(bqkv + 3072);               // 2048*64 float2 (1MB)
    ushort_t* ao    = xb;
    (void)ws_size; (void)in_sizes; (void)n_in; (void)out_size;

    // allow 128KB dynamic LDS for the 256^2 GEMM (idempotent, host-side)
    hipFuncSetAttribute((const void*)gemm_qkv_256,
                        hipFuncAttributeMaxDynamicSharedMemorySize, 131072);

    prep<<<dim3(9740), 256, 0, stream>>>(x, Wq, Wk, Wv, Wo, bq, bk, bv,
                                         xb, Wqkvb, bqkv, rtab);
    gemm_qkv_256<<<dim3((M / 256) * (NQKV / 256)), 512, 131072, stream>>>(
        xb, Wqkvb, bqkv, qkv0, M, NQKV, DMODEL);
    attn_mfma<<<dim3(BATCH * NHEADS * (SEQ / 64)), 256, 0, stream>>>(
        qkv0, qnw, knw, scp, rtab, ao);
    gemm_out_ks<<<dim3((M / 128) * (DMODEL / 128)), 512, 0, stream>>>(
        ao, Wob, bo, out, M, DMODEL, DMODEL);
}

// Round 13
// 138.326 us; speedup vs baseline: 1.2105x; 1.0092x over previous
//
#include <hip/hip_runtime.h>

// ---------------- problem constants ----------------
#define BATCH 2
#define SEQ 2048
#define DMODEL 2048
#define NHEADS 16
#define NKV 4
#define DK 128
#define WINH 64   // WINDOW/2
#define NQKV 3072 // 2048 q + 512 k + 512 v

typedef unsigned short ushort_t;
typedef __attribute__((ext_vector_type(8))) __bf16 bf16x8;
typedef __attribute__((ext_vector_type(4))) float f32x4;

__device__ __forceinline__ float b2f(ushort_t u) {
    union { unsigned int i; float f; } v; v.i = ((unsigned int)u) << 16; return v.f;
}
__device__ __forceinline__ ushort_t f2b(float f) {
    union { float f; unsigned int i; } v; v.f = f;
    unsigned int r = v.i + 0x7FFFu + ((v.i >> 16) & 1u);
    return (ushort_t)(r >> 16);
}

// async global->LDS, 16B/lane; LDS dest wave-uniform base + lane*16.
__device__ __forceinline__ void gload_lds16(const ushort_t* g, ushort_t* l) {
    __builtin_amdgcn_global_load_lds(
        (__attribute__((address_space(1))) void*)(void*)const_cast<ushort_t*>(g),
        (__attribute__((address_space(3))) void*)l, 16, 0, 0);
}

// ---------------------------------------------------------------
// prep: all input conversion in ONE launch (blockIdx ranges).
// ---------------------------------------------------------------
__global__ __launch_bounds__(256) void prep(
    const float* __restrict__ x,  const float* __restrict__ Wq,
    const float* __restrict__ Wk, const float* __restrict__ Wv,
    const float* __restrict__ Wo, const float* __restrict__ bq,
    const float* __restrict__ bk, const float* __restrict__ bv,
    ushort_t* __restrict__ xb, ushort_t* __restrict__ wdst,
    float* __restrict__ bqkv, float2* __restrict__ rtab)
{
    const int blk = blockIdx.x;
    const int tid = threadIdx.x;
    if (blk < 4096) {                               // x cast
        int i = blk * 256 + tid;
        float4 a = *((const float4*)x + i * 2);
        float4 b = *((const float4*)x + i * 2 + 1);
        ushort_t o[8] = { f2b(a.x), f2b(a.y), f2b(a.z), f2b(a.w),
                          f2b(b.x), f2b(b.y), f2b(b.z), f2b(b.w) };
        *((uint4*)xb + i) = *(const uint4*)o;
    } else if (blk < 9216) {                        // weights cast
        int i = (blk - 4096) * 256 + tid;
        int row = i >> 8, c8 = i & 255;
        const float* src;
        if      (row < 2048) src = Wq + (size_t)row * 2048;
        else if (row < 2560) src = Wk + (size_t)(row - 2048) * 2048;
        else if (row < 3072) src = Wv + (size_t)(row - 2560) * 2048;
        else                 src = Wo + (size_t)(row - 3072) * 2048;
        float4 a = *((const float4*)src + c8 * 2);
        float4 b = *((const float4*)src + c8 * 2 + 1);
        ushort_t o[8] = { f2b(a.x), f2b(a.y), f2b(a.z), f2b(a.w),
                          f2b(b.x), f2b(b.y), f2b(b.z), f2b(b.w) };
        *((uint4*)wdst + i) = *(const uint4*)o;
    } else if (blk < 9228) {                        // bias concat
        int i = (blk - 9216) * 256 + tid;
        if (i < 2048) bqkv[i] = bq[i];
        else if (i < 2560) bqkv[i] = bk[i - 2048];
        else if (i < 3072) bqkv[i] = bv[i - 2560];
    } else {                                        // rope table
        int i = (blk - 9228) * 256 + tid;           // 0..131071
        int s = i >> 6, dd = i & 63;
        float invfreq = exp2f(-(float)(2 * dd) * (13.287712379549449f / 128.0f));
        float ang = (float)s * invfreq;
        rtab[i] = make_float2(cosf(ang), sinf(ang));
    }
}

// ---------------------------------------------------------------
// QKV GEMM (R5/R9-verified ~56.5us, 912 TF): C[M][3072] = A*W^T + bias.
// 128x128 tile, BK=64, 4 waves 2x2, global_load_lds, slot s^(r&7) swizzle,
// bijective XCD swizzle. 3 blocks/CU -> cross-block overlap hides drains.
// (256^2 tile tried R11: 808 TF at 1 block/CU — reverted.)
// ---------------------------------------------------------------
__global__ __launch_bounds__(256) void gemm_qkv(
    const ushort_t* __restrict__ A, const ushort_t* __restrict__ W,
    const float* __restrict__ bias, ushort_t* __restrict__ C,
    int M, int N, int K)
{
    __shared__ __attribute__((aligned(16))) ushort_t sA[8192];
    __shared__ __attribute__((aligned(16))) ushort_t sB[8192];

    const int tid  = threadIdx.x;
    const int lane = tid & 63;
    const int wave = tid >> 6;
    const int nbn  = N >> 7;

    int nwg = gridDim.x;
    int bid = blockIdx.x;
    int nb  = (nwg & 7) ? bid : ((bid & 7) * (nwg >> 3) + (bid >> 3));
    const int bm = nb / nbn;
    const int bn = nb % nbn;
    const int m0 = bm << 7, n0 = bn << 7;
    const int wm = wave >> 1, wn = wave & 1;

    f32x4 acc[4][4] = {};

    const int frow = lane & 15;
    const int kg   = lane >> 4;

    const ushort_t* gA[4]; const ushort_t* gB[4];
    ushort_t* lA[4]; ushort_t* lB[4];
#pragma unroll
    for (int j = 0; j < 4; ++j) {
        int t = wave * 4 + j;
        int c = t * 64 + lane;
        int r = c >> 3, s = c & 7;
        int ksrc = s ^ (r & 7);
        gA[j] = A + (size_t)(m0 + r) * K + ksrc * 8;
        gB[j] = W + (size_t)(n0 + r) * K + ksrc * 8;
        lA[j] = sA + t * 512;
        lB[j] = sB + t * 512;
    }

    for (int k0 = 0; k0 < K; k0 += 64) {
        if (k0) __syncthreads();
#pragma unroll
        for (int j = 0; j < 4; ++j) gload_lds16(gA[j] + k0, lA[j]);
#pragma unroll
        for (int j = 0; j < 4; ++j) gload_lds16(gB[j] + k0, lB[j]);
        __syncthreads();

        bf16x8 af[4][2], bfr[4][2];
#pragma unroll
        for (int mi = 0; mi < 4; ++mi)
#pragma unroll
            for (int kk = 0; kk < 2; ++kk) {
                int r = (wm << 6) + (mi << 4) + frow;
                int sl = (kk * 4 + kg) ^ (r & 7);
                af[mi][kk] = *(const bf16x8*)(sA + (r * 8 + sl) * 8);
            }
#pragma unroll
        for (int ni = 0; ni < 4; ++ni)
#pragma unroll
            for (int kk = 0; kk < 2; ++kk) {
                int r = (wn << 6) + (ni << 4) + frow;
                int sl = (kk * 4 + kg) ^ (r & 7);
                bfr[ni][kk] = *(const bf16x8*)(sB + (r * 8 + sl) * 8);
            }
#pragma unroll
        for (int kk = 0; kk < 2; ++kk)
#pragma unroll
            for (int mi = 0; mi < 4; ++mi)
#pragma unroll
                for (int ni = 0; ni < 4; ++ni)
                    acc[mi][ni] = __builtin_amdgcn_mfma_f32_16x16x32_bf16(
                        af[mi][kk], bfr[ni][kk], acc[mi][ni], 0, 0, 0);
    }

    const int orow = (lane >> 4) << 2;
    const int ocol = lane & 15;
#pragma unroll
    for (int ni = 0; ni < 4; ++ni) {
        int col = n0 + (wn << 6) + (ni << 4) + ocol;
        float bvf = bias[col];
#pragma unroll
        for (int mi = 0; mi < 4; ++mi) {
#pragma unroll
            for (int r = 0; r < 4; ++r) {
                int row = m0 + (wm << 6) + (mi << 4) + orow + r;
                C[(size_t)row * N + col] = f2b(acc[mi][ni][r] + bvf);
            }
        }
    }
}

// ---------------------------------------------------------------
// Output GEMM (f32 out), split-K + DOUBLE-BUFFERED stage-early pipeline.
// 512 thr = 8 waves; group g = wave>>2 computes k-half g of each BK=64.
// LDS 64KB: staging dbuf 2x(16K A + 16K B), union'd with the 64KB
// split-K reduce buffer (safe: reduce starts after final barrier).
// Next tile's global_load_lds issued BEFORE computing current tile ->
// barrier's vmcnt(0) waits on ~600-cycle-old loads; 2 blocks/CU cover
// the rest. XCD swizzle (grid 512 % 8 == 0).
// ---------------------------------------------------------------
__global__ __launch_bounds__(512) void gemm_out_ks(
    const ushort_t* __restrict__ A, const ushort_t* __restrict__ W,
    const float* __restrict__ bias, float* __restrict__ C,
    int M, int N, int K)
{
    __shared__ __attribute__((aligned(16))) unsigned char smem[65536];
    float* red = (float*)smem;                 // used after K-loop

    const int tid  = threadIdx.x;
    const int lane = tid & 63;
    const int wave = tid >> 6;                 // 0..7
    const int g    = wave >> 2;                // k-half group
    const int q    = wave & 3;                 // quadrant
    const int wm   = q >> 1, wn = q & 1;
    const int nbn  = N >> 7;

    int nwg = gridDim.x;
    int bid = blockIdx.x;
    int nb  = (nwg & 7) ? bid : ((bid & 7) * (nwg >> 3) + (bid >> 3));
    const int bm = nb / nbn;
    const int bn = nb % nbn;
    const int m0 = bm << 7, n0 = bn << 7;

    f32x4 acc[4][4] = {};

    const int frow = lane & 15;
    const int kg   = lane >> 4;

    // staging geometry: per matrix 1024 chunks (128 rows x 8 slots);
    // wave stages 2 sets of 64 chunks. slot s stored linear, src k = s^(r&7).
    const ushort_t* gA[2]; const ushort_t* gB[2];
    int eofs[2];
#pragma unroll
    for (int j = 0; j < 2; ++j) {
        int t = wave * 2 + j;
        int c = t * 64 + lane;
        int r = c >> 3, s = c & 7;
        int ksrc = s ^ (r & 7);
        gA[j] = A + (size_t)(m0 + r) * K + ksrc * 8;
        gB[j] = W + (size_t)(n0 + r) * K + ksrc * 8;
        eofs[j] = t * 512;                     // element offset in A/B region
    }

    const int nt = K >> 6;                     // 32 tiles
    // prologue: stage tile 0 into buf 0
#pragma unroll
    for (int j = 0; j < 2; ++j) {
        gload_lds16(gA[j], (ushort_t*)smem + eofs[j]);
        gload_lds16(gB[j], (ushort_t*)(smem + 16384) + eofs[j]);
    }
    __syncthreads();

    for (int t = 0; t < nt; ++t) {
        const int cur = t & 1;
        if (t + 1 < nt) {                      // prefetch next tile FIRST
            const int nxt = cur ^ 1;
            const int ko = (t + 1) << 6;
#pragma unroll
            for (int j = 0; j < 2; ++j) {
                gload_lds16(gA[j] + ko, (ushort_t*)(smem + nxt * 32768) + eofs[j]);
                gload_lds16(gB[j] + ko, (ushort_t*)(smem + nxt * 32768 + 16384) + eofs[j]);
            }
        }
        const ushort_t* bufA = (const ushort_t*)(smem + cur * 32768);
        const ushort_t* bufB = (const ushort_t*)(smem + cur * 32768 + 16384);

        bf16x8 af[4], bfr[4];
#pragma unroll
        for (int mi = 0; mi < 4; ++mi) {
            int r = (wm << 6) + (mi << 4) + frow;
            int sl = ((g << 2) + kg) ^ (r & 7);
            af[mi] = *(const bf16x8*)(bufA + (r * 8 + sl) * 8);
        }
#pragma unroll
        for (int ni = 0; ni < 4; ++ni) {
            int r = (wn << 6) + (ni << 4) + frow;
            int sl = ((g << 2) + kg) ^ (r & 7);
            bfr[ni] = *(const bf16x8*)(bufB + (r * 8 + sl) * 8);
        }
#pragma unroll
        for (int mi = 0; mi < 4; ++mi)
#pragma unroll
            for (int ni = 0; ni < 4; ++ni)
                acc[mi][ni] = __builtin_amdgcn_mfma_f32_16x16x32_bf16(
                    af[mi], bfr[ni], acc[mi][ni], 0, 0, 0);

        __syncthreads();   // drains this tile's ds_reads + next tile's gloads
    }

    // ---- cross-group reduce via LDS (group 1 -> group 0) ----
    if (g == 1) {
#pragma unroll
        for (int mi = 0; mi < 4; ++mi)
#pragma unroll
            for (int ni = 0; ni < 4; ++ni)
                *(f32x4*)(red + q * 4096 + (mi * 4 + ni) * 256 + lane * 4) =
                    acc[mi][ni];
    }
    __syncthreads();

    if (g == 0) {
        const int orow = (lane >> 4) << 2;
        const int ocol = lane & 15;
#pragma unroll
        for (int ni = 0; ni < 4; ++ni) {
            int col = n0 + (wn << 6) + (ni << 4) + ocol;
            float bvf = bias[col];
#pragma unroll
            for (int mi = 0; mi < 4; ++mi) {
                f32x4 other = *(const f32x4*)(red + q * 4096 + (mi * 4 + ni) * 256 + lane * 4);
#pragma unroll
                for (int r = 0; r < 4; ++r) {
                    int row = m0 + (wm << 6) + (mi << 4) + orow + r;
                    C[(size_t)row * N + col] = acc[mi][ni][r] + other[r] + bvf;
                }
            }
        }
    }
}

// ---------------------------------------------------------------
// MFMA windowed-causal GQA attention WITH fused RMSNorm+RoPE (R10).
// ---------------------------------------------------------------
__global__ __launch_bounds__(256) void attn_mfma(
    const ushort_t* __restrict__ qkv, const float* __restrict__ qn_w,
    const float* __restrict__ kn_w, const float* __restrict__ scp,
    const float2* __restrict__ rtab, ushort_t* __restrict__ ao)
{
    __shared__ __attribute__((aligned(16))) ushort_t sK[16384];   // K tile, then P(f32)
    __shared__ __attribute__((aligned(16))) ushort_t sVT[16384];  // V^T tile

    const int tid  = threadIdx.x;
    const int lane = tid & 63;
    const int w    = tid >> 6;
    const int c    = lane & 15;
    const int g    = lane >> 4;

    const int blk = blockIdx.x;
    const int qt  = blk & 31;
    const int h   = (blk >> 5) & 15;
    const int b   = blk >> 9;
    const int kvh = h >> 2;
    const int i0  = qt << 6;
    const int jb  = i0 - 64;
    const float scale = scp[0];

    // ---- Q fragments: load raw, fused rmsnorm + rope + scale ----
    bf16x8 aq[4];
    {
        const int srow = i0 + w * 16 + c;                 // seq position
        const ushort_t* qp = qkv + ((size_t)(b * 2048 + srow)) * NQKV
                                 + h * 128 + g * 8;
        float xv[4][8];
        float ss = 0.f;
#pragma unroll
        for (int ks = 0; ks < 4; ++ks) {
            ushort_t raw[8];
            *(uint4*)raw = *(const uint4*)(qp + ks * 32);
#pragma unroll
            for (int j = 0; j < 8; ++j) {
                float xf = b2f(raw[j]);
                xv[ks][j] = xf;
                ss += xf * xf;
            }
        }
        ss += __shfl_xor(ss, 16, 64);
        ss += __shfl_xor(ss, 32, 64);
        float inv = rsqrtf(ss * (1.0f / 128.0f) + 1e-8f) * scale;
#pragma unroll
        for (int ks = 0; ks < 4; ++ks) {
            ushort_t outb[8];
#pragma unroll
            for (int jj = 0; jj < 4; ++jj) {
                int d = ks * 32 + g * 8 + 2 * jj;
                float2 w2 = *(const float2*)(qn_w + d);
                float x0 = xv[ks][2 * jj]     * inv * w2.x;
                float x1 = xv[ks][2 * jj + 1] * inv * w2.y;
                float2 cs = rtab[(srow << 6) + (d >> 1)];
                outb[2 * jj]     = f2b(x0 * cs.x - x1 * cs.y);
                outb[2 * jj + 1] = f2b(x0 * cs.y + x1 * cs.x);
            }
            aq[ks] = *(const bf16x8*)outb;
        }
    }

    // ---- stage K rows [key][d] with fused rmsnorm + rope ----
    const ushort_t* kvb = qkv + ((size_t)b * 2048) * NQKV + 2048 + kvh * 128;
#pragma unroll
    for (int it = 0; it < 8; ++it) {
        int idx = it * 256 + tid;
        int rr = idx >> 4, cc = idx & 15;
        int j = jb + rr; if (j < 0) j = 0;
        ushort_t raw[8];
        *(uint4*)raw = *(const uint4*)(kvb + (size_t)j * NQKV + cc * 8);
        float xv[8];
        float ss = 0.f;
#pragma unroll
        for (int jj = 0; jj < 8; ++jj) {
            xv[jj] = b2f(raw[jj]);
            ss += xv[jj] * xv[jj];
        }
        ss += __shfl_xor(ss, 1, 64);
        ss += __shfl_xor(ss, 2, 64);
        ss += __shfl_xor(ss, 4, 64);
        ss += __shfl_xor(ss, 8, 64);
        float inv = rsqrtf(ss * (1.0f / 128.0f) + 1e-8f);
        ushort_t outb[8];
#pragma unroll
        for (int jj = 0; jj < 4; ++jj) {
            int d = cc * 8 + 2 * jj;
            float2 w2 = *(const float2*)(kn_w + d);
            float x0 = xv[2 * jj]     * inv * w2.x;
            float x1 = xv[2 * jj + 1] * inv * w2.y;
            float2 cs = rtab[(j << 6) + (d >> 1)];
            outb[2 * jj]     = f2b(x0 * cs.x - x1 * cs.y);
            outb[2 * jj + 1] = f2b(x0 * cs.y + x1 * cs.x);
        }
        int f2v = (rr & 15) ^ ((rr >> 3) & 15);
        *(uint4*)(sK + (rr * 16 + (cc ^ f2v)) * 8) = *(const uint4*)outb;
    }
    // ---- stage V transposed: VT[d][key] (no norm) ----
#pragma unroll
    for (int it = 0; it < 4; ++it) {
        int task = it * 256 + tid;
        int pp = task >> 4, d8 = task & 15;
        int j0 = jb + 2 * pp;     if (j0 < 0) j0 = 0;
        int j1 = jb + 2 * pp + 1; if (j1 < 0) j1 = 0;
        ushort_t e0[8]; *(uint4*)e0 = *(const uint4*)(kvb + (size_t)j0 * NQKV + 512 + d8 * 8);
        ushort_t e1[8]; *(uint4*)e1 = *(const uint4*)(kvb + (size_t)j1 * NQKV + 512 + d8 * 8);
        int cc = pp >> 2;
#pragma unroll
        for (int jj = 0; jj < 8; ++jj) {
            int rr = d8 * 8 + jj;
            int f2v = (rr & 15) ^ ((rr >> 3) & 15);
            unsigned int word = (unsigned int)e0[jj] | ((unsigned int)e1[jj] << 16);
            *(unsigned int*)(sVT + (rr * 16 + (cc ^ f2v)) * 8 + (pp & 3) * 2) = word;
        }
    }
    __syncthreads();

    // ---- S = Q K^T (scale pre-folded into Q) ----
    f32x4 s[8] = {};
#pragma unroll
    for (int nt = 0; nt < 8; ++nt) {
        int rr = nt * 16 + c;
        int f2v = (rr & 15) ^ ((rr >> 3) & 15);
#pragma unroll
        for (int ks = 0; ks < 4; ++ks) {
            bf16x8 bk = *(const bf16x8*)(sK + (rr * 16 + ((ks * 4 + g) ^ f2v)) * 8);
            s[nt] = __builtin_amdgcn_mfma_f32_16x16x32_bf16(aq[ks], bk, s[nt], 0, 0, 0);
        }
    }

    // ---- mask + row softmax ----
    float linv[4];
#pragma unroll
    for (int r = 0; r < 4; ++r) {
        int qb = w * 16 + g * 4 + r;
#pragma unroll
        for (int nt = 0; nt < 8; ++nt) {
            int jl = nt * 16 + c;
            bool valid = (jl >= qb) && (jl <= qb + 64) && (i0 + jl >= 64);
            s[nt][r] = valid ? s[nt][r] : -1e30f;
        }
        float m = s[0][r];
#pragma unroll
        for (int nt = 1; nt < 8; ++nt) m = fmaxf(m, s[nt][r]);
#pragma unroll
        for (int off = 1; off <= 8; off <<= 1) m = fmaxf(m, __shfl_xor(m, off, 64));
        float sum = 0.f;
#pragma unroll
        for (int nt = 0; nt < 8; ++nt) {
            float e = __expf(s[nt][r] - m);
            s[nt][r] = e;
            sum += e;
        }
#pragma unroll
        for (int off = 1; off <= 8; off <<= 1) sum += __shfl_xor(sum, off, 64);
        linv[r] = 1.0f / sum;
    }

    // ---- P via LDS ----
    __syncthreads();
    float* Pw = (float*)sK + w * 2048;
#pragma unroll
    for (int nt = 0; nt < 8; ++nt) {
#pragma unroll
        for (int r = 0; r < 4; ++r) {
            int q = g * 4 + r;
            int chunk = nt * 4 + (c >> 2);
            Pw[q * 128 + ((chunk ^ (q & 7)) * 4) + (c & 3)] = s[nt][r];
        }
    }

    // ---- O = P V ----
    f32x4 o[8] = {};
#pragma unroll
    for (int kt = 0; kt < 4; ++kt) {
        float pf[8];
#pragma unroll
        for (int e = 0; e < 2; ++e) {
            int chunk = kt * 8 + g * 2 + e;
            f32x4 v4 = *(const f32x4*)(Pw + c * 128 + ((chunk ^ (c & 7)) * 4));
            pf[e * 4 + 0] = v4[0]; pf[e * 4 + 1] = v4[1];
            pf[e * 4 + 2] = v4[2]; pf[e * 4 + 3] = v4[3];
        }
        ushort_t pb[8];
#pragma unroll
        for (int j = 0; j < 8; ++j) pb[j] = f2b(pf[j]);
        bf16x8 pa = *(const bf16x8*)pb;
#pragma unroll
        for (int dt = 0; dt < 8; ++dt) {
            int rr = dt * 16 + c;
            int f2v = (rr & 15) ^ ((rr >> 3) & 15);
            bf16x8 bv = *(const bf16x8*)(sVT + (rr * 16 + ((kt * 4 + g) ^ f2v)) * 8);
            o[dt] = __builtin_amdgcn_mfma_f32_16x16x32_bf16(pa, bv, o[dt], 0, 0, 0);
        }
    }

    // ---- epilogue ----
    const size_t orow0 = (size_t)(b * 2048 + i0 + w * 16);
#pragma unroll
    for (int dt = 0; dt < 8; ++dt) {
#pragma unroll
        for (int r = 0; r < 4; ++r) {
            int q = g * 4 + r;
            ao[(orow0 + q) * 2048 + h * 128 + dt * 16 + c] = f2b(o[dt][r] * linv[r]);
        }
    }
}

// ---------------------------------------------------------------
extern "C" void kernel_launch(void* const* d_in, const int* in_sizes, int n_in,
                              void* d_out, int out_size, void* d_ws, size_t ws_size,
                              hipStream_t stream)
{
    const float* x   = (const float*)d_in[0];
    const float* Wq  = (const float*)d_in[1];
    const float* bq  = (const float*)d_in[2];
    const float* Wk  = (const float*)d_in[3];
    const float* bk  = (const float*)d_in[4];
    const float* Wv  = (const float*)d_in[5];
    const float* bv  = (const float*)d_in[6];
    const float* Wo  = (const float*)d_in[7];
    const float* bo  = (const float*)d_in[8];
    const float* qnw = (const float*)d_in[9];
    const float* knw = (const float*)d_in[10];
    const float* scp = (const float*)d_in[11];
    float* out = (float*)d_out;

    const int M = BATCH * SEQ;             // 4096
    ushort_t* xb    = (ushort_t*)d_ws;                      // M x 2048 (later: ao)
    ushort_t* qkv0  = xb   + (size_t)M * DMODEL;            // M x 3072 (raw)
    ushort_t* Wqkvb = qkv0 + (size_t)M * NQKV;              // 3072 x 2048
    ushort_t* Wob   = Wqkvb + (size_t)NQKV * DMODEL;        // 2048 x 2048
    float*    bqkv  = (float*)(Wob + (size_t)DMODEL * DMODEL); // 3072 f32
    float2*   rtab  = (float2*)(bqkv + 3072);               // 2048*64 float2 (1MB)
    ushort_t* ao    = xb;
    (void)ws_size; (void)in_sizes; (void)n_in; (void)out_size;

    prep<<<dim3(9740), 256, 0, stream>>>(x, Wq, Wk, Wv, Wo, bq, bk, bv,
                                         xb, Wqkvb, bqkv, rtab);
    gemm_qkv<<<dim3((M / 128) * (NQKV / 128)), 256, 0, stream>>>(
        xb, Wqkvb, bqkv, qkv0, M, NQKV, DMODEL);
    attn_mfma<<<dim3(BATCH * NHEADS * (SEQ / 64)), 256, 0, stream>>>(
        qkv0, qnw, knw, scp, rtab, ao);
    gemm_out_ks<<<dim3((M / 128) * (DMODEL / 128)), 512, 0, stream>>>(
        ao, Wob, bo, out, M, DMODEL, DMODEL);
}

// Round 14
// 136.307 us; speedup vs baseline: 1.2284x; 1.0148x over previous
//
#include <hip/hip_runtime.h>

// ---------------- problem constants ----------------
#define BATCH 2
#define SEQ 2048
#define DMODEL 2048
#define NHEADS 16
#define NKV 4
#define DK 128
#define WINH 64   // WINDOW/2
#define NQKV 3072 // 2048 q + 512 k + 512 v

typedef unsigned short ushort_t;
typedef __attribute__((ext_vector_type(8))) __bf16 bf16x8;
typedef __attribute__((ext_vector_type(4))) float f32x4;

__device__ __forceinline__ float b2f(ushort_t u) {
    union { unsigned int i; float f; } v; v.i = ((unsigned int)u) << 16; return v.f;
}
__device__ __forceinline__ ushort_t f2b(float f) {
    union { float f; unsigned int i; } v; v.f = f;
    unsigned int r = v.i + 0x7FFFu + ((v.i >> 16) & 1u);
    return (ushort_t)(r >> 16);
}

// async global->LDS, 16B/lane; LDS dest wave-uniform base + lane*16.
__device__ __forceinline__ void gload_lds16(const ushort_t* g, ushort_t* l) {
    __builtin_amdgcn_global_load_lds(
        (__attribute__((address_space(1))) void*)(void*)const_cast<ushort_t*>(g),
        (__attribute__((address_space(3))) void*)l, 16, 0, 0);
}

// ---------------------------------------------------------------
// prep: all input conversion in ONE launch (blockIdx ranges).
// ---------------------------------------------------------------
__global__ __launch_bounds__(256) void prep(
    const float* __restrict__ x,  const float* __restrict__ Wq,
    const float* __restrict__ Wk, const float* __restrict__ Wv,
    const float* __restrict__ Wo, const float* __restrict__ bq,
    const float* __restrict__ bk, const float* __restrict__ bv,
    ushort_t* __restrict__ xb, ushort_t* __restrict__ wdst,
    float* __restrict__ bqkv, float2* __restrict__ rtab)
{
    const int blk = blockIdx.x;
    const int tid = threadIdx.x;
    if (blk < 4096) {                               // x cast
        int i = blk * 256 + tid;
        float4 a = *((const float4*)x + i * 2);
        float4 b = *((const float4*)x + i * 2 + 1);
        ushort_t o[8] = { f2b(a.x), f2b(a.y), f2b(a.z), f2b(a.w),
                          f2b(b.x), f2b(b.y), f2b(b.z), f2b(b.w) };
        *((uint4*)xb + i) = *(const uint4*)o;
    } else if (blk < 9216) {                        // weights cast
        int i = (blk - 4096) * 256 + tid;
        int row = i >> 8, c8 = i & 255;
        const float* src;
        if      (row < 2048) src = Wq + (size_t)row * 2048;
        else if (row < 2560) src = Wk + (size_t)(row - 2048) * 2048;
        else if (row < 3072) src = Wv + (size_t)(row - 2560) * 2048;
        else                 src = Wo + (size_t)(row - 3072) * 2048;
        float4 a = *((const float4*)src + c8 * 2);
        float4 b = *((const float4*)src + c8 * 2 + 1);
        ushort_t o[8] = { f2b(a.x), f2b(a.y), f2b(a.z), f2b(a.w),
                          f2b(b.x), f2b(b.y), f2b(b.z), f2b(b.w) };
        *((uint4*)wdst + i) = *(const uint4*)o;
    } else if (blk < 9228) {                        // bias concat
        int i = (blk - 9216) * 256 + tid;
        if (i < 2048) bqkv[i] = bq[i];
        else if (i < 2560) bqkv[i] = bk[i - 2048];
        else if (i < 3072) bqkv[i] = bv[i - 2560];
    } else {                                        // rope table
        int i = (blk - 9228) * 256 + tid;           // 0..131071
        int s = i >> 6, dd = i & 63;
        float invfreq = exp2f(-(float)(2 * dd) * (13.287712379549449f / 128.0f));
        float ang = (float)s * invfreq;
        rtab[i] = make_float2(cosf(ang), sinf(ang));
    }
}

// ---------------------------------------------------------------
// QKV GEMM, 256x192 tile, counted-vmcnt deep pipeline.
// 512 thr = 8 waves (2M x 4N); per-wave output 128x48 (acc[8][3]).
// BK=64. LDS 112KB: A dbuf 2x32KB at 0, B dbuf 2x24KB at 64KB.
// Grid 16x16 = 256 blocks = exactly 1 block/CU (fixes R11's 75% fill).
// Pipeline (T3/T4): issue stage(t+1) -> s_waitcnt vmcnt(7) (counted:
// waits only tile t's 7 loads, issued a full compute-step ago; the 7
// new loads stay in flight ACROSS both raw s_barriers — this is the
// fix for R11, where __syncthreads' vmcnt(0) drained the prefetch).
// End of step: lgkmcnt(0) + s_barrier protects buf from next DMA write.
// Conflict-free chunk swizzle slot = s^(r&7) (0 conflicts, R11-measured).
// Bijective XCD swizzle (256 % 8 == 0).
// ---------------------------------------------------------------
__global__ __launch_bounds__(512) void gemm_qkv_p(
    const ushort_t* __restrict__ A, const ushort_t* __restrict__ W,
    const float* __restrict__ bias, ushort_t* __restrict__ C,
    int M, int N, int K)
{
    extern __shared__ __attribute__((aligned(16))) ushort_t smem[];
    // element offsets: A buf p at p*16384 (32KB); B buf p at 32768 + p*12288 (24KB)

    const int tid  = threadIdx.x;
    const int lane = tid & 63;
    const int wave = tid >> 6;          // 0..7
    const int wm   = wave >> 2;         // 0..1 -> rows wm*128
    const int wn   = wave & 3;          // 0..3 -> cols wn*48
    const int nbn  = N / 192;           // 16

    int nwg = gridDim.x;
    int bid = blockIdx.x;
    int nb  = (nwg & 7) ? bid : ((bid & 7) * (nwg >> 3) + (bid >> 3));
    const int bm = nb / nbn;
    const int bn = nb % nbn;
    const int m0 = bm << 8;
    const int n0 = bn * 192;

    f32x4 acc[8][3] = {};

    const int frow = lane & 15;
    const int kg   = lane >> 4;

    // staging: A = 2048 chunks of 16B (256 rows x 8 slots), 4 rounds;
    //          B = 1536 chunks (192 rows x 8 slots), 3 rounds.
    // chunk c: r=c>>3, store slot c&7 linear, source k-slot (c&7)^(r&7).
    const ushort_t* gA[4]; const ushort_t* gB[3];
    int aofs[4], bofs[3];
#pragma unroll
    for (int j = 0; j < 4; ++j) {
        int c = j * 512 + tid;
        int r = c >> 3, s = c & 7;
        gA[j] = A + (size_t)(m0 + r) * K + (s ^ (r & 7)) * 8;
        aofs[j] = (j * 512 + wave * 64) * 8;     // wave-uniform element base
    }
#pragma unroll
    for (int j = 0; j < 3; ++j) {
        int c = j * 512 + tid;
        int r = c >> 3, s = c & 7;
        gB[j] = W + (size_t)(n0 + r) * K + (s ^ (r & 7)) * 8;
        bofs[j] = (j * 512 + wave * 64) * 8;
    }

    const int nt = K >> 6;                       // 32 K-steps
    // prologue: stage tile 0 into buf 0 (7 loads/thread)
#pragma unroll
    for (int j = 0; j < 4; ++j) gload_lds16(gA[j], smem + aofs[j]);
#pragma unroll
    for (int j = 0; j < 3; ++j) gload_lds16(gB[j], smem + 32768 + bofs[j]);

    for (int t = 0; t < nt; ++t) {
        const int cur = t & 1;
        if (t + 1 < nt) {
            // issue next-tile loads FIRST (stage-early); they stay in
            // flight across both barriers below (counted vmcnt).
            const int nxt = cur ^ 1;
            const int ko = (t + 1) << 6;
#pragma unroll
            for (int j = 0; j < 4; ++j)
                gload_lds16(gA[j] + ko, smem + nxt * 16384 + aofs[j]);
#pragma unroll
            for (int j = 0; j < 3; ++j)
                gload_lds16(gB[j] + ko, smem + 32768 + nxt * 12288 + bofs[j]);
            asm volatile("s_waitcnt vmcnt(7)" ::: "memory");   // tile t landed
        } else {
            asm volatile("s_waitcnt vmcnt(0)" ::: "memory");   // last tile: drain
        }
        __builtin_amdgcn_s_barrier();            // buf[cur] ready block-wide
        __builtin_amdgcn_sched_barrier(0);

        const ushort_t* bufA = smem + cur * 16384;
        const ushort_t* bufB = smem + 32768 + cur * 12288;
#pragma unroll
        for (int kk = 0; kk < 2; ++kk) {
            bf16x8 af[8], bf[3];
#pragma unroll
            for (int mf = 0; mf < 8; ++mf) {
                int r = wm * 128 + mf * 16 + frow;
                af[mf] = *(const bf16x8*)(bufA + (r * 8 + ((kk * 4 + kg) ^ (r & 7))) * 8);
            }
#pragma unroll
            for (int nf = 0; nf < 3; ++nf) {
                int r = wn * 48 + nf * 16 + frow;
                bf[nf] = *(const bf16x8*)(bufB + (r * 8 + ((kk * 4 + kg) ^ (r & 7))) * 8);
            }
#pragma unroll
            for (int mf = 0; mf < 8; ++mf)
#pragma unroll
                for (int nf = 0; nf < 3; ++nf)
                    acc[mf][nf] = __builtin_amdgcn_mfma_f32_16x16x32_bf16(
                        af[mf], bf[nf], acc[mf][nf], 0, 0, 0);
        }
        // all this step's LDS reads complete, then block-wide fence so the
        // NEXT iteration's DMA writes into buf[cur^1... (t+2)&1==cur] are safe.
        asm volatile("s_waitcnt lgkmcnt(0)" ::: "memory");
        __builtin_amdgcn_s_barrier();
        __builtin_amdgcn_sched_barrier(0);
    }

    // D: col = lane&15, row = (lane>>4)*4 + reg  [m89-verified]
    const int orow = (lane >> 4) << 2;
    const int ocol = lane & 15;
#pragma unroll
    for (int nf = 0; nf < 3; ++nf) {
        int col = n0 + wn * 48 + nf * 16 + ocol;
        float bvf = bias[col];
#pragma unroll
        for (int mf = 0; mf < 8; ++mf) {
#pragma unroll
            for (int r = 0; r < 4; ++r) {
                int row = m0 + wm * 128 + mf * 16 + orow + r;
                C[(size_t)row * N + col] = f2b(acc[mf][nf][r] + bvf);
            }
        }
    }
}

// ---------------------------------------------------------------
// Output GEMM (f32 out), split-K + double-buffered stage-early (R12).
// ---------------------------------------------------------------
__global__ __launch_bounds__(512) void gemm_out_ks(
    const ushort_t* __restrict__ A, const ushort_t* __restrict__ W,
    const float* __restrict__ bias, float* __restrict__ C,
    int M, int N, int K)
{
    __shared__ __attribute__((aligned(16))) unsigned char smem[65536];
    float* red = (float*)smem;                 // used after K-loop

    const int tid  = threadIdx.x;
    const int lane = tid & 63;
    const int wave = tid >> 6;                 // 0..7
    const int g    = wave >> 2;                // k-half group
    const int q    = wave & 3;                 // quadrant
    const int wm   = q >> 1, wn = q & 1;
    const int nbn  = N >> 7;

    int nwg = gridDim.x;
    int bid = blockIdx.x;
    int nb  = (nwg & 7) ? bid : ((bid & 7) * (nwg >> 3) + (bid >> 3));
    const int bm = nb / nbn;
    const int bn = nb % nbn;
    const int m0 = bm << 7, n0 = bn << 7;

    f32x4 acc[4][4] = {};

    const int frow = lane & 15;
    const int kg   = lane >> 4;

    const ushort_t* gA[2]; const ushort_t* gB[2];
    int eofs[2];
#pragma unroll
    for (int j = 0; j < 2; ++j) {
        int t = wave * 2 + j;
        int c = t * 64 + lane;
        int r = c >> 3, s = c & 7;
        int ksrc = s ^ (r & 7);
        gA[j] = A + (size_t)(m0 + r) * K + ksrc * 8;
        gB[j] = W + (size_t)(n0 + r) * K + ksrc * 8;
        eofs[j] = t * 512;
    }

    const int nt = K >> 6;
#pragma unroll
    for (int j = 0; j < 2; ++j) {
        gload_lds16(gA[j], (ushort_t*)smem + eofs[j]);
        gload_lds16(gB[j], (ushort_t*)(smem + 16384) + eofs[j]);
    }
    __syncthreads();

    for (int t = 0; t < nt; ++t) {
        const int cur = t & 1;
        if (t + 1 < nt) {
            const int nxt = cur ^ 1;
            const int ko = (t + 1) << 6;
#pragma unroll
            for (int j = 0; j < 2; ++j) {
                gload_lds16(gA[j] + ko, (ushort_t*)(smem + nxt * 32768) + eofs[j]);
                gload_lds16(gB[j] + ko, (ushort_t*)(smem + nxt * 32768 + 16384) + eofs[j]);
            }
        }
        const ushort_t* bufA = (const ushort_t*)(smem + cur * 32768);
        const ushort_t* bufB = (const ushort_t*)(smem + cur * 32768 + 16384);

        bf16x8 af[4], bfr[4];
#pragma unroll
        for (int mi = 0; mi < 4; ++mi) {
            int r = (wm << 6) + (mi << 4) + frow;
            int sl = ((g << 2) + kg) ^ (r & 7);
            af[mi] = *(const bf16x8*)(bufA + (r * 8 + sl) * 8);
        }
#pragma unroll
        for (int ni = 0; ni < 4; ++ni) {
            int r = (wn << 6) + (ni << 4) + frow;
            int sl = ((g << 2) + kg) ^ (r & 7);
            bfr[ni] = *(const bf16x8*)(bufB + (r * 8 + sl) * 8);
        }
#pragma unroll
        for (int mi = 0; mi < 4; ++mi)
#pragma unroll
            for (int ni = 0; ni < 4; ++ni)
                acc[mi][ni] = __builtin_amdgcn_mfma_f32_16x16x32_bf16(
                    af[mi], bfr[ni], acc[mi][ni], 0, 0, 0);

        __syncthreads();
    }

    if (g == 1) {
#pragma unroll
        for (int mi = 0; mi < 4; ++mi)
#pragma unroll
            for (int ni = 0; ni < 4; ++ni)
                *(f32x4*)(red + q * 4096 + (mi * 4 + ni) * 256 + lane * 4) =
                    acc[mi][ni];
    }
    __syncthreads();

    if (g == 0) {
        const int orow = (lane >> 4) << 2;
        const int ocol = lane & 15;
#pragma unroll
        for (int ni = 0; ni < 4; ++ni) {
            int col = n0 + (wn << 6) + (ni << 4) + ocol;
            float bvf = bias[col];
#pragma unroll
            for (int mi = 0; mi < 4; ++mi) {
                f32x4 other = *(const f32x4*)(red + q * 4096 + (mi * 4 + ni) * 256 + lane * 4);
#pragma unroll
                for (int r = 0; r < 4; ++r) {
                    int row = m0 + (wm << 6) + (mi << 4) + orow + r;
                    C[(size_t)row * N + col] = acc[mi][ni][r] + other[r] + bvf;
                }
            }
        }
    }
}

// ---------------------------------------------------------------
// MFMA windowed-causal GQA attention WITH fused RMSNorm+RoPE (R10).
// ---------------------------------------------------------------
__global__ __launch_bounds__(256) void attn_mfma(
    const ushort_t* __restrict__ qkv, const float* __restrict__ qn_w,
    const float* __restrict__ kn_w, const float* __restrict__ scp,
    const float2* __restrict__ rtab, ushort_t* __restrict__ ao)
{
    __shared__ __attribute__((aligned(16))) ushort_t sK[16384];   // K tile, then P(f32)
    __shared__ __attribute__((aligned(16))) ushort_t sVT[16384];  // V^T tile

    const int tid  = threadIdx.x;
    const int lane = tid & 63;
    const int w    = tid >> 6;
    const int c    = lane & 15;
    const int g    = lane >> 4;

    const int blk = blockIdx.x;
    const int qt  = blk & 31;
    const int h   = (blk >> 5) & 15;
    const int b   = blk >> 9;
    const int kvh = h >> 2;
    const int i0  = qt << 6;
    const int jb  = i0 - 64;
    const float scale = scp[0];

    // ---- Q fragments: load raw, fused rmsnorm + rope + scale ----
    bf16x8 aq[4];
    {
        const int srow = i0 + w * 16 + c;                 // seq position
        const ushort_t* qp = qkv + ((size_t)(b * 2048 + srow)) * NQKV
                                 + h * 128 + g * 8;
        float xv[4][8];
        float ss = 0.f;
#pragma unroll
        for (int ks = 0; ks < 4; ++ks) {
            ushort_t raw[8];
            *(uint4*)raw = *(const uint4*)(qp + ks * 32);
#pragma unroll
            for (int j = 0; j < 8; ++j) {
                float xf = b2f(raw[j]);
                xv[ks][j] = xf;
                ss += xf * xf;
            }
        }
        ss += __shfl_xor(ss, 16, 64);
        ss += __shfl_xor(ss, 32, 64);
        float inv = rsqrtf(ss * (1.0f / 128.0f) + 1e-8f) * scale;
#pragma unroll
        for (int ks = 0; ks < 4; ++ks) {
            ushort_t outb[8];
#pragma unroll
            for (int jj = 0; jj < 4; ++jj) {
                int d = ks * 32 + g * 8 + 2 * jj;
                float2 w2 = *(const float2*)(qn_w + d);
                float x0 = xv[ks][2 * jj]     * inv * w2.x;
                float x1 = xv[ks][2 * jj + 1] * inv * w2.y;
                float2 cs = rtab[(srow << 6) + (d >> 1)];
                outb[2 * jj]     = f2b(x0 * cs.x - x1 * cs.y);
                outb[2 * jj + 1] = f2b(x0 * cs.y + x1 * cs.x);
            }
            aq[ks] = *(const bf16x8*)outb;
        }
    }

    // ---- stage K rows [key][d] with fused rmsnorm + rope ----
    const ushort_t* kvb = qkv + ((size_t)b * 2048) * NQKV + 2048 + kvh * 128;
#pragma unroll
    for (int it = 0; it < 8; ++it) {
        int idx = it * 256 + tid;
        int rr = idx >> 4, cc = idx & 15;
        int j = jb + rr; if (j < 0) j = 0;
        ushort_t raw[8];
        *(uint4*)raw = *(const uint4*)(kvb + (size_t)j * NQKV + cc * 8);
        float xv[8];
        float ss = 0.f;
#pragma unroll
        for (int jj = 0; jj < 8; ++jj) {
            xv[jj] = b2f(raw[jj]);
            ss += xv[jj] * xv[jj];
        }
        ss += __shfl_xor(ss, 1, 64);
        ss += __shfl_xor(ss, 2, 64);
        ss += __shfl_xor(ss, 4, 64);
        ss += __shfl_xor(ss, 8, 64);
        float inv = rsqrtf(ss * (1.0f / 128.0f) + 1e-8f);
        ushort_t outb[8];
#pragma unroll
        for (int jj = 0; jj < 4; ++jj) {
            int d = cc * 8 + 2 * jj;
            float2 w2 = *(const float2*)(kn_w + d);
            float x0 = xv[2 * jj]     * inv * w2.x;
            float x1 = xv[2 * jj + 1] * inv * w2.y;
            float2 cs = rtab[(j << 6) + (d >> 1)];
            outb[2 * jj]     = f2b(x0 * cs.x - x1 * cs.y);
            outb[2 * jj + 1] = f2b(x0 * cs.y + x1 * cs.x);
        }
        int f2v = (rr & 15) ^ ((rr >> 3) & 15);
        *(uint4*)(sK + (rr * 16 + (cc ^ f2v)) * 8) = *(const uint4*)outb;
    }
    // ---- stage V transposed: VT[d][key] (no norm) ----
#pragma unroll
    for (int it = 0; it < 4; ++it) {
        int task = it * 256 + tid;
        int pp = task >> 4, d8 = task & 15;
        int j0 = jb + 2 * pp;     if (j0 < 0) j0 = 0;
        int j1 = jb + 2 * pp + 1; if (j1 < 0) j1 = 0;
        ushort_t e0[8]; *(uint4*)e0 = *(const uint4*)(kvb + (size_t)j0 * NQKV + 512 + d8 * 8);
        ushort_t e1[8]; *(uint4*)e1 = *(const uint4*)(kvb + (size_t)j1 * NQKV + 512 + d8 * 8);
        int cc = pp >> 2;
#pragma unroll
        for (int jj = 0; jj < 8; ++jj) {
            int rr = d8 * 8 + jj;
            int f2v = (rr & 15) ^ ((rr >> 3) & 15);
            unsigned int word = (unsigned int)e0[jj] | ((unsigned int)e1[jj] << 16);
            *(unsigned int*)(sVT + (rr * 16 + (cc ^ f2v)) * 8 + (pp & 3) * 2) = word;
        }
    }
    __syncthreads();

    // ---- S = Q K^T (scale pre-folded into Q) ----
    f32x4 s[8] = {};
#pragma unroll
    for (int nt = 0; nt < 8; ++nt) {
        int rr = nt * 16 + c;
        int f2v = (rr & 15) ^ ((rr >> 3) & 15);
#pragma unroll
        for (int ks = 0; ks < 4; ++ks) {
            bf16x8 bk = *(const bf16x8*)(sK + (rr * 16 + ((ks * 4 + g) ^ f2v)) * 8);
            s[nt] = __builtin_amdgcn_mfma_f32_16x16x32_bf16(aq[ks], bk, s[nt], 0, 0, 0);
        }
    }

    // ---- mask + row softmax ----
    float linv[4];
#pragma unroll
    for (int r = 0; r < 4; ++r) {
        int qb = w * 16 + g * 4 + r;
#pragma unroll
        for (int nt = 0; nt < 8; ++nt) {
            int jl = nt * 16 + c;
            bool valid = (jl >= qb) && (jl <= qb + 64) && (i0 + jl >= 64);
            s[nt][r] = valid ? s[nt][r] : -1e30f;
        }
        float m = s[0][r];
#pragma unroll
        for (int nt = 1; nt < 8; ++nt) m = fmaxf(m, s[nt][r]);
#pragma unroll
        for (int off = 1; off <= 8; off <<= 1) m = fmaxf(m, __shfl_xor(m, off, 64));
        float sum = 0.f;
#pragma unroll
        for (int nt = 0; nt < 8; ++nt) {
            float e = __expf(s[nt][r] - m);
            s[nt][r] = e;
            sum += e;
        }
#pragma unroll
        for (int off = 1; off <= 8; off <<= 1) sum += __shfl_xor(sum, off, 64);
        linv[r] = 1.0f / sum;
    }

    // ---- P via LDS ----
    __syncthreads();
    float* Pw = (float*)sK + w * 2048;
#pragma unroll
    for (int nt = 0; nt < 8; ++nt) {
#pragma unroll
        for (int r = 0; r < 4; ++r) {
            int q = g * 4 + r;
            int chunk = nt * 4 + (c >> 2);
            Pw[q * 128 + ((chunk ^ (q & 7)) * 4) + (c & 3)] = s[nt][r];
        }
    }

    // ---- O = P V ----
    f32x4 o[8] = {};
#pragma unroll
    for (int kt = 0; kt < 4; ++kt) {
        float pf[8];
#pragma unroll
        for (int e = 0; e < 2; ++e) {
            int chunk = kt * 8 + g * 2 + e;
            f32x4 v4 = *(const f32x4*)(Pw + c * 128 + ((chunk ^ (c & 7)) * 4));
            pf[e * 4 + 0] = v4[0]; pf[e * 4 + 1] = v4[1];
            pf[e * 4 + 2] = v4[2]; pf[e * 4 + 3] = v4[3];
        }
        ushort_t pb[8];
#pragma unroll
        for (int j = 0; j < 8; ++j) pb[j] = f2b(pf[j]);
        bf16x8 pa = *(const bf16x8*)pb;
#pragma unroll
        for (int dt = 0; dt < 8; ++dt) {
            int rr = dt * 16 + c;
            int f2v = (rr & 15) ^ ((rr >> 3) & 15);
            bf16x8 bv = *(const bf16x8*)(sVT + (rr * 16 + ((kt * 4 + g) ^ f2v)) * 8);
            o[dt] = __builtin_amdgcn_mfma_f32_16x16x32_bf16(pa, bv, o[dt], 0, 0, 0);
        }
    }

    // ---- epilogue ----
    const size_t orow0 = (size_t)(b * 2048 + i0 + w * 16);
#pragma unroll
    for (int dt = 0; dt < 8; ++dt) {
#pragma unroll
        for (int r = 0; r < 4; ++r) {
            int q = g * 4 + r;
            ao[(orow0 + q) * 2048 + h * 128 + dt * 16 + c] = f2b(o[dt][r] * linv[r]);
        }
    }
}

// ---------------------------------------------------------------
extern "C" void kernel_launch(void* const* d_in, const int* in_sizes, int n_in,
                              void* d_out, int out_size, void* d_ws, size_t ws_size,
                              hipStream_t stream)
{
    const float* x   = (const float*)d_in[0];
    const float* Wq  = (const float*)d_in[1];
    const float* bq  = (const float*)d_in[2];
    const float* Wk  = (const float*)d_in[3];
    const float* bk  = (const float*)d_in[4];
    const float* Wv  = (const float*)d_in[5];
    const float* bv  = (const float*)d_in[6];
    const float* Wo  = (const float*)d_in[7];
    const float* bo  = (const float*)d_in[8];
    const float* qnw = (const float*)d_in[9];
    const float* knw = (const float*)d_in[10];
    const float* scp = (const float*)d_in[11];
    float* out = (float*)d_out;

    const int M = BATCH * SEQ;             // 4096
    ushort_t* xb    = (ushort_t*)d_ws;                      // M x 2048 (later: ao)
    ushort_t* qkv0  = xb   + (size_t)M * DMODEL;            // M x 3072 (raw)
    ushort_t* Wqkvb = qkv0 + (size_t)M * NQKV;              // 3072 x 2048
    ushort_t* Wob   = Wqkvb + (size_t)NQKV * DMODEL;        // 2048 x 2048
    float*    bqkv  = (float*)(Wob + (size_t)DMODEL * DMODEL); // 3072 f32
    float2*   rtab  = (float2*)(bqkv + 3072);               // 2048*64 float2 (1MB)
    ushort_t* ao    = xb;
    (void)ws_size; (void)in_sizes; (void)n_in; (void)out_size;

    // allow 112KB dynamic LDS for the pipelined GEMM (host-side, idempotent)
    hipFuncSetAttribute((const void*)gemm_qkv_p,
                        hipFuncAttributeMaxDynamicSharedMemorySize, 114688);

    prep<<<dim3(9740), 256, 0, stream>>>(x, Wq, Wk, Wv, Wo, bq, bk, bv,
                                         xb, Wqkvb, bqkv, rtab);
    gemm_qkv_p<<<dim3((M / 256) * (NQKV / 192)), 512, 114688, stream>>>(
        xb, Wqkvb, bqkv, qkv0, M, NQKV, DMODEL);
    attn_mfma<<<dim3(BATCH * NHEADS * (SEQ / 64)), 256, 0, stream>>>(
        qkv0, qnw, knw, scp, rtab, ao);
    gemm_out_ks<<<dim3((M / 128) * (DMODEL / 128)), 512, 0, stream>>>(
        ao, Wob, bo, out, M, DMODEL, DMODEL);
}